// Round 2
// baseline (2883.356 us; speedup 1.0000x reference)
//
#include <hip/hip_runtime.h>

// ---------------------------------------------------------------------------
// VQ-VAE forward (fp32, NCHW). Round 2: fix workspace overflow (268.5 MB ->
// 192 MiB) via buffer liveness reuse + in-place VQ. Compute kernels unchanged.
//   conv1  [N,2,256,256] -> [N,32,128,128]  k3 s2 p1 + relu
//   conv2  -> [N,64,64,64]                  k3 s2 p1 + relu
//   conv3  -> [N,128,32,32]                 k3 s2 p1 + relu
//   conv4  -> [N,128,32,32]                 k3 s1 p1 + relu
//   VQ: rows of 64 consecutive elems of [N,128,32*32]; argmin over 512 codes
//   dec1   -> [N,64,64,64]   convT k3 s2 p1 op1 + relu
//   dec2   -> [N,32,128,128] + relu
//   dec3   -> [N,1,256,256]
// ---------------------------------------------------------------------------

template<int CIN, int COUT, int OCT, int H, int W, int S, bool RELU>
__global__ __launch_bounds__(256) void conv3x3(const float* __restrict__ in,
                                               const float* __restrict__ wgt,
                                               const float* __restrict__ bias,
                                               float* __restrict__ out, int N) {
  constexpr int OH = (S == 2) ? H / 2 : H;
  constexpr int OW = (S == 2) ? W / 2 : W;
  constexpr int TILES = COUT / OCT;
  int t = blockIdx.x * 256 + threadIdx.x;
  if (t >= N * TILES * OH * OW) return;
  const int ow = t % OW;
  int tmp = t / OW;
  const int oh = tmp % OH; tmp /= OH;
  const int tc = tmp % TILES;
  const int n  = tmp / TILES;
  // tc is wave-uniform (OH*OW % 64 == 0); force SGPR so weights become s_load
  const int oc0 = __builtin_amdgcn_readfirstlane(tc * OCT);

  const int ih0 = S * oh - 1, iw0 = S * ow - 1;
  float acc[OCT];
#pragma unroll
  for (int o = 0; o < OCT; ++o) acc[o] = bias[oc0 + o];

  const float* ip = in + (size_t)(n * CIN) * H * W;
  for (int ic = 0; ic < CIN; ++ic, ip += H * W) {
    float v[9];
#pragma unroll
    for (int kh = 0; kh < 3; ++kh) {
      const int ih = ih0 + kh;
#pragma unroll
      for (int kw = 0; kw < 3; ++kw) {
        const int iw = iw0 + kw;
        const bool ok = (ih >= 0) && (ih < H) && (iw >= 0) && (iw < W);
        v[kh * 3 + kw] = ok ? ip[ih * W + iw] : 0.f;
      }
    }
    const float* wp = wgt + ((oc0 * CIN + ic) * 9);
#pragma unroll
    for (int o = 0; o < OCT; ++o) {
      float s = acc[o];
#pragma unroll
      for (int k = 0; k < 9; ++k) s = fmaf(v[k], wp[o * CIN * 9 + k], s);
      acc[o] = s;
    }
  }
  float* op = out + ((size_t)(n * COUT + oc0) * OH + oh) * OW + ow;
#pragma unroll
  for (int o = 0; o < OCT; ++o) {
    float r = acc[o];
    if (RELU) r = fmaxf(r, 0.f);
    op[(size_t)o * OH * OW] = r;
  }
}

// Transposed conv k3 s2 p1 op1, gather form: thread owns a 2x2 output quad.
// wgt layout: [CIN][COUT][3][3]
template<int CIN, int COUT, int OCT, int IH, int IW, bool RELU>
__global__ __launch_bounds__(256) void deconv3x3(const float* __restrict__ in,
                                                 const float* __restrict__ wgt,
                                                 const float* __restrict__ bias,
                                                 float* __restrict__ out, int N) {
  constexpr int OH = 2 * IH, OW = 2 * IW;
  constexpr int TILES = COUT / OCT;
  int t = blockIdx.x * 256 + threadIdx.x;
  if (t >= N * TILES * IH * IW) return;
  const int j = t % IW;
  int tmp = t / IW;
  const int i = tmp % IH; tmp /= IH;
  const int tc = tmp % TILES;
  const int n  = tmp / TILES;
  const int oc0 = __builtin_amdgcn_readfirstlane(tc * OCT);

  float a00[OCT], a01[OCT], a10[OCT], a11[OCT];
#pragma unroll
  for (int o = 0; o < OCT; ++o) {
    const float b = bias[oc0 + o];
    a00[o] = b; a01[o] = b; a10[o] = b; a11[o] = b;
  }
  const bool rg = (j + 1) < IW;
  const bool bg = (i + 1) < IH;

  const float* ip = in + ((size_t)(n * CIN) * IH + i) * IW + j;
  for (int ic = 0; ic < CIN; ++ic, ip += IH * IW) {
    const float x00 = ip[0];
    const float x01 = rg ? ip[1] : 0.f;
    const float x10 = bg ? ip[IW] : 0.f;
    const float x11 = (rg && bg) ? ip[IW + 1] : 0.f;
    const float* wp = wgt + (ic * COUT + oc0) * 9;
#pragma unroll
    for (int o = 0; o < OCT; ++o) {
      const float* wo = wp + o * 9;
      a00[o] = fmaf(x00, wo[4], a00[o]);
      a01[o] = fmaf(x00, wo[5], fmaf(x01, wo[3], a01[o]));
      a10[o] = fmaf(x00, wo[7], fmaf(x10, wo[1], a10[o]));
      a11[o] = fmaf(x00, wo[8], fmaf(x01, wo[6], fmaf(x10, wo[2], fmaf(x11, wo[0], a11[o]))));
    }
  }
  float* op = out + ((size_t)(n * COUT + oc0) * OH + 2 * i) * OW + 2 * j;
#pragma unroll
  for (int o = 0; o < OCT; ++o) {
    float r00 = a00[o], r01 = a01[o], r10 = a10[o], r11 = a11[o];
    if (RELU) {
      r00 = fmaxf(r00, 0.f); r01 = fmaxf(r01, 0.f);
      r10 = fmaxf(r10, 0.f); r11 = fmaxf(r11, 0.f);
    }
    float* q = op + (size_t)o * OH * OW;
    q[0] = r00; q[1] = r01; q[OW] = r10; q[OW + 1] = r11;
  }
}

__global__ __launch_bounds__(256) void vq_norms(const float* __restrict__ emb,
                                                float* __restrict__ norms) {
  int jj = blockIdx.x * 256 + threadIdx.x;
  if (jj < 512) {
    float s = 0.f;
    const float* e = emb + jj * 64;
#pragma unroll
    for (int k = 0; k < 64; ++k) s = fmaf(e[k], e[k], s);
    norms[jj] = s;
  }
}

// one thread = one row (64 floats); emb staged in LDS 128 codes at a time.
// score = ||e||^2 - 2 f.e  (|f|^2 constant per row, dropped); strict < scan
// ascending matches numpy argmin first-min tie-break. In-place safe: each
// thread reads only its own row before writing only its own row.
__global__ __launch_bounds__(256) void vq_assign(const float* __restrict__ enc,
                                                 const float* __restrict__ emb,
                                                 const float* __restrict__ norms,
                                                 float* __restrict__ out, int NROWS) {
  __shared__ float se[128 * 64];  // 32 KB chunk
  const int row = blockIdx.x * 256 + threadIdx.x;
  float4 fv[16];
  const float4* fp = (const float4*)(enc + (size_t)row * 64);
#pragma unroll
  for (int q = 0; q < 16; ++q) fv[q] = fp[q];

  float best = 3.4e38f;
  int bidx = 0;
  for (int ch = 0; ch < 4; ++ch) {
    __syncthreads();
    const float4* ep = (const float4*)(emb + ch * 128 * 64);
    float4* sp = (float4*)se;
#pragma unroll
    for (int q = 0; q < 8; ++q) sp[threadIdx.x + q * 256] = ep[threadIdx.x + q * 256];
    __syncthreads();
    for (int c = 0; c < 128; ++c) {
      const float4* cp = (const float4*)(se + c * 64);
      float d = 0.f;
#pragma unroll
      for (int q = 0; q < 16; ++q) {
        const float4 e = cp[q];
        d = fmaf(fv[q].x, e.x, d);
        d = fmaf(fv[q].y, e.y, d);
        d = fmaf(fv[q].z, e.z, d);
        d = fmaf(fv[q].w, e.w, d);
      }
      const float score = norms[ch * 128 + c] - 2.f * d;
      if (score < best) { best = score; bidx = ch * 128 + c; }
    }
  }
  if (row < NROWS) {
    const float4* qp = (const float4*)(emb + (size_t)bidx * 64);
    float4* op = (float4*)(out + (size_t)row * 64);
#pragma unroll
    for (int q = 0; q < 16; ++q) op[q] = qp[q];
  }
}

extern "C" void kernel_launch(void* const* d_in, const int* in_sizes, int n_in,
                              void* d_out, int out_size, void* d_ws, size_t ws_size,
                              hipStream_t stream) {
  const float* x   = (const float*)d_in[0];
  const float* w1  = (const float*)d_in[1];
  const float* b1  = (const float*)d_in[2];
  const float* w2  = (const float*)d_in[3];
  const float* b2  = (const float*)d_in[4];
  const float* w3  = (const float*)d_in[5];
  const float* b3  = (const float*)d_in[6];
  const float* w4  = (const float*)d_in[7];
  const float* b4  = (const float*)d_in[8];
  const float* emb = (const float*)d_in[9];
  const float* dw1 = (const float*)d_in[10];
  const float* db1 = (const float*)d_in[11];
  const float* dw2 = (const float*)d_in[12];
  const float* db2 = (const float*)d_in[13];
  const float* dw3 = (const float*)d_in[14];
  const float* db3 = (const float*)d_in[15];
  float* outp = (float*)d_out;

  const int N = in_sizes[0] / (2 * 256 * 256);  // 64

  // ---- workspace layout (floats), aggressive liveness reuse ----
  // F_H1 = N*32*128*128 (134.2 MB), F_H2 = N*64*64*64 (67.1 MB),
  // F_H3 = N*128*32*32 (33.6 MB)
  const size_t F_H1 = (size_t)N * 32 * 128 * 128;
  const size_t F_H2 = (size_t)N * 64 * 64 * 64;
  const size_t F_H3 = (size_t)N * 128 * 32 * 32;
  const size_t need_bytes = (F_H1 + F_H2 + 512) * sizeof(float);  // ~192 MiB
  if (ws_size < need_bytes) return;  // avoid OOB crash; fails absmax cleanly

  float* ws  = (float*)d_ws;
  float* h1  = ws;               // [0, F_H1)               conv1 out
  float* h2  = ws + F_H1;        // [F_H1, F_H1+F_H2)       conv2 out
  float* h3  = ws;               // reuse h1 (dead after conv2)   conv3 out
  float* enc = ws + F_H3;        // [F_H3, 2*F_H3)          conv4 out
  float* vq  = enc;              // VQ in-place
  float* dd1 = ws + F_H1;        // reuse h2 (dead after conv3)   dec1 out
  float* dd2 = ws;               // reuse h3/enc (dead after dec1) dec2 out
  float* nrm = ws + F_H1 + F_H2; // 512 floats

  const int NROWS = (int)(F_H3 / 64);  // 131072

  // encoder
  conv3x3<2, 32, 32, 256, 256, 2, true>
      <<<N * 1 * 128 * 128 / 256, 256, 0, stream>>>(x, w1, b1, h1, N);
  conv3x3<32, 64, 64, 128, 128, 2, true>
      <<<N * 1 * 64 * 64 / 256, 256, 0, stream>>>(h1, w2, b2, h2, N);
  conv3x3<64, 128, 64, 64, 64, 2, true>
      <<<N * 2 * 32 * 32 / 256, 256, 0, stream>>>(h2, w3, b3, h3, N);
  conv3x3<128, 128, 64, 32, 32, 1, true>
      <<<N * 2 * 32 * 32 / 256, 256, 0, stream>>>(h3, w4, b4, enc, N);

  // VQ
  vq_norms<<<2, 256, 0, stream>>>(emb, nrm);
  vq_assign<<<NROWS / 256, 256, 0, stream>>>(enc, emb, nrm, vq, NROWS);

  // decoder
  deconv3x3<128, 64, 16, 32, 32, true>
      <<<N * 4 * 32 * 32 / 256, 256, 0, stream>>>(vq, dw1, db1, dd1, N);
  deconv3x3<64, 32, 16, 64, 64, true>
      <<<N * 2 * 64 * 64 / 256, 256, 0, stream>>>(dd1, dw2, db2, dd2, N);
  deconv3x3<32, 1, 1, 128, 128, false>
      <<<N * 1 * 128 * 128 / 256, 256, 0, stream>>>(dd2, dw3, db3, outp, N);
}

// Round 3
// 1580.357 us; speedup vs baseline: 1.8245x; 1.8245x over previous
//
#include <hip/hip_runtime.h>

// ---------------------------------------------------------------------------
// VQ-VAE forward (fp32, NCHW). Round 3: kill scratch spills — OCT 64->16 in
// conv3x3 (acc fits in VGPRs), deconv quad tile 16->8. R2 post-mortem: conv4
// showed VGPR=56 with acc[64] declared => spilled, VALUBusy 12%.
// ---------------------------------------------------------------------------

template<int CIN, int COUT, int OCT, int H, int W, int S, bool RELU>
__global__ __launch_bounds__(256) void conv3x3(const float* __restrict__ in,
                                               const float* __restrict__ wgt,
                                               const float* __restrict__ bias,
                                               float* __restrict__ out, int N) {
  constexpr int OH = (S == 2) ? H / 2 : H;
  constexpr int OW = (S == 2) ? W / 2 : W;
  constexpr int TILES = COUT / OCT;
  int t = blockIdx.x * 256 + threadIdx.x;
  if (t >= N * TILES * OH * OW) return;
  const int ow = t % OW;
  int tmp = t / OW;
  const int oh = tmp % OH; tmp /= OH;
  const int tc = tmp % TILES;
  const int n  = tmp / TILES;
  // tc is wave-uniform (OH*OW % 64 == 0); force SGPR so weights become s_load
  const int oc0 = __builtin_amdgcn_readfirstlane(tc * OCT);

  const int ih0 = S * oh - 1, iw0 = S * ow - 1;
  float acc[OCT];
#pragma unroll
  for (int o = 0; o < OCT; ++o) acc[o] = bias[oc0 + o];

  const float* ip = in + (size_t)(n * CIN) * H * W;
  for (int ic = 0; ic < CIN; ++ic, ip += H * W) {
    float v[9];
#pragma unroll
    for (int kh = 0; kh < 3; ++kh) {
      const int ih = ih0 + kh;
#pragma unroll
      for (int kw = 0; kw < 3; ++kw) {
        const int iw = iw0 + kw;
        const bool ok = (ih >= 0) && (ih < H) && (iw >= 0) && (iw < W);
        v[kh * 3 + kw] = ok ? ip[ih * W + iw] : 0.f;
      }
    }
    const float* wp = wgt + ((oc0 * CIN + ic) * 9);
#pragma unroll
    for (int o = 0; o < OCT; ++o) {
      float s = acc[o];
#pragma unroll
      for (int k = 0; k < 9; ++k) s = fmaf(v[k], wp[o * CIN * 9 + k], s);
      acc[o] = s;
    }
  }
  float* op = out + ((size_t)(n * COUT + oc0) * OH + oh) * OW + ow;
#pragma unroll
  for (int o = 0; o < OCT; ++o) {
    float r = acc[o];
    if (RELU) r = fmaxf(r, 0.f);
    op[(size_t)o * OH * OW] = r;
  }
}

// Transposed conv k3 s2 p1 op1, gather form: thread owns a 2x2 output quad.
// wgt layout: [CIN][COUT][3][3]
template<int CIN, int COUT, int OCT, int IH, int IW, bool RELU>
__global__ __launch_bounds__(256) void deconv3x3(const float* __restrict__ in,
                                                 const float* __restrict__ wgt,
                                                 const float* __restrict__ bias,
                                                 float* __restrict__ out, int N) {
  constexpr int OH = 2 * IH, OW = 2 * IW;
  constexpr int TILES = COUT / OCT;
  int t = blockIdx.x * 256 + threadIdx.x;
  if (t >= N * TILES * IH * IW) return;
  const int j = t % IW;
  int tmp = t / IW;
  const int i = tmp % IH; tmp /= IH;
  const int tc = tmp % TILES;
  const int n  = tmp / TILES;
  const int oc0 = __builtin_amdgcn_readfirstlane(tc * OCT);

  float a00[OCT], a01[OCT], a10[OCT], a11[OCT];
#pragma unroll
  for (int o = 0; o < OCT; ++o) {
    const float b = bias[oc0 + o];
    a00[o] = b; a01[o] = b; a10[o] = b; a11[o] = b;
  }
  const bool rg = (j + 1) < IW;
  const bool bg = (i + 1) < IH;

  const float* ip = in + ((size_t)(n * CIN) * IH + i) * IW + j;
  for (int ic = 0; ic < CIN; ++ic, ip += IH * IW) {
    const float x00 = ip[0];
    const float x01 = rg ? ip[1] : 0.f;
    const float x10 = bg ? ip[IW] : 0.f;
    const float x11 = (rg && bg) ? ip[IW + 1] : 0.f;
    const float* wp = wgt + (ic * COUT + oc0) * 9;
#pragma unroll
    for (int o = 0; o < OCT; ++o) {
      const float* wo = wp + o * 9;
      a00[o] = fmaf(x00, wo[4], a00[o]);
      a01[o] = fmaf(x00, wo[5], fmaf(x01, wo[3], a01[o]));
      a10[o] = fmaf(x00, wo[7], fmaf(x10, wo[1], a10[o]));
      a11[o] = fmaf(x00, wo[8], fmaf(x01, wo[6], fmaf(x10, wo[2], fmaf(x11, wo[0], a11[o]))));
    }
  }
  float* op = out + ((size_t)(n * COUT + oc0) * OH + 2 * i) * OW + 2 * j;
#pragma unroll
  for (int o = 0; o < OCT; ++o) {
    float r00 = a00[o], r01 = a01[o], r10 = a10[o], r11 = a11[o];
    if (RELU) {
      r00 = fmaxf(r00, 0.f); r01 = fmaxf(r01, 0.f);
      r10 = fmaxf(r10, 0.f); r11 = fmaxf(r11, 0.f);
    }
    float* q = op + (size_t)o * OH * OW;
    q[0] = r00; q[1] = r01; q[OW] = r10; q[OW + 1] = r11;
  }
}

__global__ __launch_bounds__(256) void vq_norms(const float* __restrict__ emb,
                                                float* __restrict__ norms) {
  int jj = blockIdx.x * 256 + threadIdx.x;
  if (jj < 512) {
    float s = 0.f;
    const float* e = emb + jj * 64;
#pragma unroll
    for (int k = 0; k < 64; ++k) s = fmaf(e[k], e[k], s);
    norms[jj] = s;
  }
}

// one thread = one row (64 floats); emb staged in LDS 128 codes at a time.
// score = ||e||^2 - 2 f.e ; strict < scan ascending matches numpy argmin
// tie-break. In-place safe (thread reads only its own row before writing it).
__global__ __launch_bounds__(256) void vq_assign(const float* __restrict__ enc,
                                                 const float* __restrict__ emb,
                                                 const float* __restrict__ norms,
                                                 float* __restrict__ out, int NROWS) {
  __shared__ float se[128 * 64];  // 32 KB chunk
  const int row = blockIdx.x * 256 + threadIdx.x;
  float4 fv[16];
  const float4* fp = (const float4*)(enc + (size_t)row * 64);
#pragma unroll
  for (int q = 0; q < 16; ++q) fv[q] = fp[q];

  float best = 3.4e38f;
  int bidx = 0;
  for (int ch = 0; ch < 4; ++ch) {
    __syncthreads();
    const float4* ep = (const float4*)(emb + ch * 128 * 64);
    float4* sp = (float4*)se;
#pragma unroll
    for (int q = 0; q < 8; ++q) sp[threadIdx.x + q * 256] = ep[threadIdx.x + q * 256];
    __syncthreads();
    for (int c = 0; c < 128; ++c) {
      const float4* cp = (const float4*)(se + c * 64);
      float d = 0.f;
#pragma unroll
      for (int q = 0; q < 16; ++q) {
        const float4 e = cp[q];
        d = fmaf(fv[q].x, e.x, d);
        d = fmaf(fv[q].y, e.y, d);
        d = fmaf(fv[q].z, e.z, d);
        d = fmaf(fv[q].w, e.w, d);
      }
      const float score = norms[ch * 128 + c] - 2.f * d;
      if (score < best) { best = score; bidx = ch * 128 + c; }
    }
  }
  if (row < NROWS) {
    const float4* qp = (const float4*)(emb + (size_t)bidx * 64);
    float4* op = (float4*)(out + (size_t)row * 64);
#pragma unroll
    for (int q = 0; q < 16; ++q) op[q] = qp[q];
  }
}

extern "C" void kernel_launch(void* const* d_in, const int* in_sizes, int n_in,
                              void* d_out, int out_size, void* d_ws, size_t ws_size,
                              hipStream_t stream) {
  const float* x   = (const float*)d_in[0];
  const float* w1  = (const float*)d_in[1];
  const float* b1  = (const float*)d_in[2];
  const float* w2  = (const float*)d_in[3];
  const float* b2  = (const float*)d_in[4];
  const float* w3  = (const float*)d_in[5];
  const float* b3  = (const float*)d_in[6];
  const float* w4  = (const float*)d_in[7];
  const float* b4  = (const float*)d_in[8];
  const float* emb = (const float*)d_in[9];
  const float* dw1 = (const float*)d_in[10];
  const float* db1 = (const float*)d_in[11];
  const float* dw2 = (const float*)d_in[12];
  const float* db2 = (const float*)d_in[13];
  const float* dw3 = (const float*)d_in[14];
  const float* db3 = (const float*)d_in[15];
  float* outp = (float*)d_out;

  const int N = in_sizes[0] / (2 * 256 * 256);  // 64

  // ---- workspace layout (floats), liveness reuse; peak 192 MiB ----
  const size_t F_H1 = (size_t)N * 32 * 128 * 128;
  const size_t F_H2 = (size_t)N * 64 * 64 * 64;
  const size_t F_H3 = (size_t)N * 128 * 32 * 32;
  const size_t need_bytes = (F_H1 + F_H2 + 512) * sizeof(float);
  if (ws_size < need_bytes) return;

  float* ws  = (float*)d_ws;
  float* h1  = ws;               // conv1 out
  float* h2  = ws + F_H1;        // conv2 out
  float* h3  = ws;               // reuse h1 (dead after conv2)
  float* enc = ws + F_H3;        // conv4 out
  float* vq  = enc;              // VQ in-place
  float* dd1 = ws + F_H1;        // reuse h2
  float* dd2 = ws;               // reuse h3/enc
  float* nrm = ws + F_H1 + F_H2;

  const int NROWS = (int)(F_H3 / 64);  // 131072

  // encoder (OCT=16: 16 acc + 9 window regs, no spill)
  conv3x3<2, 32, 16, 256, 256, 2, true>
      <<<N * 2 * 128 * 128 / 256, 256, 0, stream>>>(x, w1, b1, h1, N);
  conv3x3<32, 64, 16, 128, 128, 2, true>
      <<<N * 4 * 64 * 64 / 256, 256, 0, stream>>>(h1, w2, b2, h2, N);
  conv3x3<64, 128, 16, 64, 64, 2, true>
      <<<N * 8 * 32 * 32 / 256, 256, 0, stream>>>(h2, w3, b3, h3, N);
  conv3x3<128, 128, 16, 32, 32, 1, true>
      <<<N * 8 * 32 * 32 / 256, 256, 0, stream>>>(h3, w4, b4, enc, N);

  // VQ
  vq_norms<<<2, 256, 0, stream>>>(emb, nrm);
  vq_assign<<<NROWS / 256, 256, 0, stream>>>(enc, emb, nrm, vq, NROWS);

  // decoder (OCT=8: 32 acc regs)
  deconv3x3<128, 64, 8, 32, 32, true>
      <<<N * 8 * 32 * 32 / 256, 256, 0, stream>>>(vq, dw1, db1, dd1, N);
  deconv3x3<64, 32, 8, 64, 64, true>
      <<<N * 4 * 64 * 64 / 256, 256, 0, stream>>>(dd1, dw2, db2, dd2, N);
  deconv3x3<32, 1, 1, 128, 128, false>
      <<<N * 1 * 128 * 128 / 256, 256, 0, stream>>>(dd2, dw3, db3, outp, N);
}

// Round 4
// 1385.659 us; speedup vs baseline: 2.0809x; 1.1405x over previous
//
#include <hip/hip_runtime.h>

// ---------------------------------------------------------------------------
// VQ-VAE forward (NCHW). Round 4: conv4 -> MFMA implicit GEMM, split-bf16
// (hi+lo, 3 products) for ~1e-5 relative accuracy (conv4 feeds VQ argmin).
// Pre-passes pack weights in A-fragment order and X in padded [n][34x34][ic]
// layout so the main loop is pure global->reg->MFMA (no LDS, no barriers).
// Everything else unchanged from R3 (fp32 direct).
// ---------------------------------------------------------------------------

using short8  = __attribute__((ext_vector_type(8))) short;
using floatx4 = __attribute__((ext_vector_type(4))) float;

__device__ inline unsigned short bf16rn(float f) {
  unsigned u = __float_as_uint(f);
  unsigned r = (u + 0x7fffu + ((u >> 16) & 1u)) >> 16;
  return (unsigned short)r;
}

// ------------------------- fp32 direct conv (R3) ---------------------------
template<int CIN, int COUT, int OCT, int H, int W, int S, bool RELU>
__global__ __launch_bounds__(256) void conv3x3(const float* __restrict__ in,
                                               const float* __restrict__ wgt,
                                               const float* __restrict__ bias,
                                               float* __restrict__ out, int N) {
  constexpr int OH = (S == 2) ? H / 2 : H;
  constexpr int OW = (S == 2) ? W / 2 : W;
  constexpr int TILES = COUT / OCT;
  int t = blockIdx.x * 256 + threadIdx.x;
  if (t >= N * TILES * OH * OW) return;
  const int ow = t % OW;
  int tmp = t / OW;
  const int oh = tmp % OH; tmp /= OH;
  const int tc = tmp % TILES;
  const int n  = tmp / TILES;
  const int oc0 = __builtin_amdgcn_readfirstlane(tc * OCT);

  const int ih0 = S * oh - 1, iw0 = S * ow - 1;
  float acc[OCT];
#pragma unroll
  for (int o = 0; o < OCT; ++o) acc[o] = bias[oc0 + o];

  const float* ip = in + (size_t)(n * CIN) * H * W;
  for (int ic = 0; ic < CIN; ++ic, ip += H * W) {
    float v[9];
#pragma unroll
    for (int kh = 0; kh < 3; ++kh) {
      const int ih = ih0 + kh;
#pragma unroll
      for (int kw = 0; kw < 3; ++kw) {
        const int iw = iw0 + kw;
        const bool ok = (ih >= 0) && (ih < H) && (iw >= 0) && (iw < W);
        v[kh * 3 + kw] = ok ? ip[ih * W + iw] : 0.f;
      }
    }
    const float* wp = wgt + ((oc0 * CIN + ic) * 9);
#pragma unroll
    for (int o = 0; o < OCT; ++o) {
      float s = acc[o];
#pragma unroll
      for (int k = 0; k < 9; ++k) s = fmaf(v[k], wp[o * CIN * 9 + k], s);
      acc[o] = s;
    }
  }
  float* op = out + ((size_t)(n * COUT + oc0) * OH + oh) * OW + ow;
#pragma unroll
  for (int o = 0; o < OCT; ++o) {
    float r = acc[o];
    if (RELU) r = fmaxf(r, 0.f);
    op[(size_t)o * OH * OW] = r;
  }
}

template<int CIN, int COUT, int OCT, int IH, int IW, bool RELU>
__global__ __launch_bounds__(256) void deconv3x3(const float* __restrict__ in,
                                                 const float* __restrict__ wgt,
                                                 const float* __restrict__ bias,
                                                 float* __restrict__ out, int N) {
  constexpr int OH = 2 * IH, OW = 2 * IW;
  constexpr int TILES = COUT / OCT;
  int t = blockIdx.x * 256 + threadIdx.x;
  if (t >= N * TILES * IH * IW) return;
  const int j = t % IW;
  int tmp = t / IW;
  const int i = tmp % IH; tmp /= IH;
  const int tc = tmp % TILES;
  const int n  = tmp / TILES;
  const int oc0 = __builtin_amdgcn_readfirstlane(tc * OCT);

  float a00[OCT], a01[OCT], a10[OCT], a11[OCT];
#pragma unroll
  for (int o = 0; o < OCT; ++o) {
    const float b = bias[oc0 + o];
    a00[o] = b; a01[o] = b; a10[o] = b; a11[o] = b;
  }
  const bool rg = (j + 1) < IW;
  const bool bg = (i + 1) < IH;

  const float* ip = in + ((size_t)(n * CIN) * IH + i) * IW + j;
  for (int ic = 0; ic < CIN; ++ic, ip += IH * IW) {
    const float x00 = ip[0];
    const float x01 = rg ? ip[1] : 0.f;
    const float x10 = bg ? ip[IW] : 0.f;
    const float x11 = (rg && bg) ? ip[IW + 1] : 0.f;
    const float* wp = wgt + (ic * COUT + oc0) * 9;
#pragma unroll
    for (int o = 0; o < OCT; ++o) {
      const float* wo = wp + o * 9;
      a00[o] = fmaf(x00, wo[4], a00[o]);
      a01[o] = fmaf(x00, wo[5], fmaf(x01, wo[3], a01[o]));
      a10[o] = fmaf(x00, wo[7], fmaf(x10, wo[1], a10[o]));
      a11[o] = fmaf(x00, wo[8], fmaf(x01, wo[6], fmaf(x10, wo[2], fmaf(x11, wo[0], a11[o]))));
    }
  }
  float* op = out + ((size_t)(n * COUT + oc0) * OH + 2 * i) * OW + 2 * j;
#pragma unroll
  for (int o = 0; o < OCT; ++o) {
    float r00 = a00[o], r01 = a01[o], r10 = a10[o], r11 = a11[o];
    if (RELU) {
      r00 = fmaxf(r00, 0.f); r01 = fmaxf(r01, 0.f);
      r10 = fmaxf(r10, 0.f); r11 = fmaxf(r11, 0.f);
    }
    float* q = op + (size_t)o * OH * OW;
    q[0] = r00; q[1] = r01; q[OW] = r10; q[OW + 1] = r11;
  }
}

// ------------------------------- VQ (R3) -----------------------------------
__global__ __launch_bounds__(256) void vq_norms(const float* __restrict__ emb,
                                                float* __restrict__ norms) {
  int jj = blockIdx.x * 256 + threadIdx.x;
  if (jj < 512) {
    float s = 0.f;
    const float* e = emb + jj * 64;
#pragma unroll
    for (int k = 0; k < 64; ++k) s = fmaf(e[k], e[k], s);
    norms[jj] = s;
  }
}

__global__ __launch_bounds__(256) void vq_assign(const float* __restrict__ enc,
                                                 const float* __restrict__ emb,
                                                 const float* __restrict__ norms,
                                                 float* __restrict__ out, int NROWS) {
  __shared__ float se[128 * 64];
  const int row = blockIdx.x * 256 + threadIdx.x;
  float4 fv[16];
  const float4* fp = (const float4*)(enc + (size_t)row * 64);
#pragma unroll
  for (int q = 0; q < 16; ++q) fv[q] = fp[q];

  float best = 3.4e38f;
  int bidx = 0;
  for (int ch = 0; ch < 4; ++ch) {
    __syncthreads();
    const float4* ep = (const float4*)(emb + ch * 128 * 64);
    float4* sp = (float4*)se;
#pragma unroll
    for (int q = 0; q < 8; ++q) sp[threadIdx.x + q * 256] = ep[threadIdx.x + q * 256];
    __syncthreads();
    for (int c = 0; c < 128; ++c) {
      const float4* cp = (const float4*)(se + c * 64);
      float d = 0.f;
#pragma unroll
      for (int q = 0; q < 16; ++q) {
        const float4 e = cp[q];
        d = fmaf(fv[q].x, e.x, d);
        d = fmaf(fv[q].y, e.y, d);
        d = fmaf(fv[q].z, e.z, d);
        d = fmaf(fv[q].w, e.w, d);
      }
      const float score = norms[ch * 128 + c] - 2.f * d;
      if (score < best) { best = score; bidx = ch * 128 + c; }
    }
  }
  if (row < NROWS) {
    const float4* qp = (const float4*)(emb + (size_t)bidx * 64);
    float4* op = (float4*)(out + (size_t)row * 64);
#pragma unroll
    for (int q = 0; q < 16; ++q) op[q] = qp[q];
  }
}

// ----------------------- conv4 MFMA path (new) -----------------------------
// Pack w4 [128cout][128cin][3][3] fp32 into split-bf16 A-fragments.
// Frag index: t = ((s*8 + mt)*64 + lane)*8 + j, s = icb*9 + (kh*3+kw),
// A[m = mt*16 + (lane&15)][k], k -> ic = icb*32 + quad*8 + j, tap (kh,kw).
__global__ __launch_bounds__(256) void w4_prep(const float* __restrict__ w,
                                               short* __restrict__ hi,
                                               short* __restrict__ lo) {
  const int t = blockIdx.x * 256 + threadIdx.x;  // < 36*8*64*8 = 147456
  const int j  = t & 7;
  const int l  = (t >> 3) & 63;
  const int mt = (t >> 9) & 7;
  const int s  = t >> 12;           // 0..35
  const int icb = s / 9, tap = s - icb * 9;
  const int kh = tap / 3, kw = tap - kh * 3;
  const int m  = mt * 16 + (l & 15);
  const int ic = icb * 32 + ((l >> 4) & 3) * 8 + j;
  const float v = w[((m * 128 + ic) * 3 + kh) * 3 + kw];
  const unsigned short h = bf16rn(v);
  hi[t] = (short)h;
  lo[t] = (short)bf16rn(v - __uint_as_float((unsigned)h << 16));
}

// Transpose+pad+split h3 [N][128][32][32] fp32 -> [N][34][34][128] bf16 hi/lo.
__global__ __launch_bounds__(256) void xt_prep(const float* __restrict__ x,
                                               short* __restrict__ hi,
                                               short* __restrict__ lo, int total) {
  const int t = blockIdx.x * 256 + threadIdx.x;
  if (t >= total) return;                 // total = N*34*34*128
  const int ic = t & 127;
  int pp = t >> 7;
  const int cc = pp % 34; pp /= 34;
  const int rr = pp % 34;
  const int n  = pp / 34;
  const int r = rr - 1, c = cc - 1;
  float v = 0.f;
  if (r >= 0 && r < 32 && c >= 0 && c < 32)
    v = x[(((size_t)n * 128 + ic) * 32 + r) * 32 + c];
  const unsigned short h = bf16rn(v);
  hi[t] = (short)h;
  lo[t] = (short)bf16rn(v - __uint_as_float((unsigned)h << 16));
}

// C[cout=128][pix] per image; block = 64 pixels (2 rows), 4 waves x 16 px.
// Per wave: 8 m-tiles of 16x16, K = 9 taps x 128 ic, split-bf16 (3 MFMAs).
__global__ __launch_bounds__(256) void conv4_mfma(
    const short* __restrict__ xthi, const short* __restrict__ xtlo,
    const short* __restrict__ ahi,  const short* __restrict__ alo,
    const float* __restrict__ bias, float* __restrict__ out) {
  const int b    = blockIdx.x;
  const int n    = b >> 4;
  const int pt   = b & 15;                 // 64-pixel tile -> rows 2pt,2pt+1
  const int lane = threadIdx.x & 63;
  const int wave = threadIdx.x >> 6;
  const int pl   = wave * 16 + (lane & 15);  // local pixel 0..63
  const int r    = 2 * pt + (pl >> 5);
  const int c    = pl & 31;
  const int kq   = lane >> 4;              // quad 0..3

  floatx4 acc[8];
#pragma unroll
  for (int mt = 0; mt < 8; ++mt) acc[mt] = (floatx4){0.f, 0.f, 0.f, 0.f};

  // B element base: [n][r+kh][c+kw][icb*32 + kq*8], tap adds (kh*34+kw)*128
  const size_t bbase = (((size_t)n * 34 + r) * 34 + c) * 128 + kq * 8;
  const short8* __restrict__ ah8 = (const short8*)ahi;
  const short8* __restrict__ al8 = (const short8*)alo;

  int s = 0;
  for (int icb = 0; icb < 4; ++icb) {
#pragma unroll
    for (int tap = 0; tap < 9; ++tap, ++s) {
      const int kh = tap / 3, kw = tap - kh * 3;
      const size_t be = bbase + (size_t)(kh * 34 + kw) * 128 + icb * 32;
      const short8 bh = *(const short8*)(xthi + be);
      const short8 bl = *(const short8*)(xtlo + be);
#pragma unroll
      for (int mt = 0; mt < 8; ++mt) {
        const int fi = ((s * 8 + mt) << 6) + lane;
        const short8 ah = ah8[fi];
        const short8 al = al8[fi];
        acc[mt] = __builtin_amdgcn_mfma_f32_16x16x32_bf16(ah, bh, acc[mt], 0, 0, 0);
        acc[mt] = __builtin_amdgcn_mfma_f32_16x16x32_bf16(ah, bl, acc[mt], 0, 0, 0);
        acc[mt] = __builtin_amdgcn_mfma_f32_16x16x32_bf16(al, bh, acc[mt], 0, 0, 0);
      }
    }
  }

  // D: row(m within tile) = kq*4+q, col(n) = lane&15 -> pixel pl
  float* op = out + (size_t)n * 128 * 1024 + (pt * 64 + pl);
#pragma unroll
  for (int mt = 0; mt < 8; ++mt) {
#pragma unroll
    for (int q = 0; q < 4; ++q) {
      const int cout = mt * 16 + kq * 4 + q;
      op[(size_t)cout * 1024] = fmaxf(acc[mt][q] + bias[cout], 0.f);
    }
  }
}

// ---------------------------------------------------------------------------
extern "C" void kernel_launch(void* const* d_in, const int* in_sizes, int n_in,
                              void* d_out, int out_size, void* d_ws, size_t ws_size,
                              hipStream_t stream) {
  const float* x   = (const float*)d_in[0];
  const float* w1  = (const float*)d_in[1];
  const float* b1  = (const float*)d_in[2];
  const float* w2  = (const float*)d_in[3];
  const float* b2  = (const float*)d_in[4];
  const float* w3  = (const float*)d_in[5];
  const float* b3  = (const float*)d_in[6];
  const float* w4  = (const float*)d_in[7];
  const float* b4  = (const float*)d_in[8];
  const float* emb = (const float*)d_in[9];
  const float* dw1 = (const float*)d_in[10];
  const float* db1 = (const float*)d_in[11];
  const float* dw2 = (const float*)d_in[12];
  const float* db2 = (const float*)d_in[13];
  const float* dw3 = (const float*)d_in[14];
  const float* db3 = (const float*)d_in[15];
  float* outp = (float*)d_out;

  const int N = in_sizes[0] / (2 * 256 * 256);  // 64

  const size_t F_H1 = (size_t)N * 32 * 128 * 128;
  const size_t F_H2 = (size_t)N * 64 * 64 * 64;
  const size_t F_H3 = (size_t)N * 128 * 32 * 32;
  const size_t AFRAG = 36 * 8 * 64 * 8;                 // 147456 shorts/split
  const size_t XTOT  = (size_t)N * 34 * 34 * 128;       // padded XT elements
  const size_t need_bytes = (F_H1 + F_H2 + 512 + AFRAG) * sizeof(float);
  if (ws_size < need_bytes) return;

  float* ws  = (float*)d_ws;
  float* h1  = ws;               // conv1 out
  float* h2  = ws + F_H1;        // conv2 out
  float* h3  = ws;               // reuse h1 (dead after conv2)
  float* enc = ws + F_H3;        // conv4 out
  float* vq  = enc;              // VQ in-place
  float* dd1 = ws + F_H1;        // reuse h2
  float* dd2 = ws;               // reuse h3/enc
  float* nrm = ws + F_H1 + F_H2;
  // conv4 scratch: XT hi/lo live in the dead hole [2*F_H3, F_H1) (67 MB free)
  short* xthi = (short*)(ws + 2 * F_H3);
  short* xtlo = xthi + XTOT;                            // 2*XTOT shorts = 37.9 MB
  short* ahi  = (short*)(ws + F_H1 + F_H2 + 512);
  short* alo  = ahi + AFRAG;

  const int NROWS = (int)(F_H3 / 64);  // 131072

  // encoder
  conv3x3<2, 32, 16, 256, 256, 2, true>
      <<<N * 2 * 128 * 128 / 256, 256, 0, stream>>>(x, w1, b1, h1, N);
  conv3x3<32, 64, 16, 128, 128, 2, true>
      <<<N * 4 * 64 * 64 / 256, 256, 0, stream>>>(h1, w2, b2, h2, N);
  conv3x3<64, 128, 16, 64, 64, 2, true>
      <<<N * 8 * 32 * 32 / 256, 256, 0, stream>>>(h2, w3, b3, h3, N);

  // conv4 via MFMA split-bf16
  w4_prep<<<(int)(AFRAG / 256), 256, 0, stream>>>(w4, ahi, alo);
  xt_prep<<<(int)((XTOT + 255) / 256), 256, 0, stream>>>(h3, xthi, xtlo, (int)XTOT);
  conv4_mfma<<<N * 16, 256, 0, stream>>>(xthi, xtlo, ahi, alo, b4, enc);

  // VQ
  vq_norms<<<2, 256, 0, stream>>>(emb, nrm);
  vq_assign<<<NROWS / 256, 256, 0, stream>>>(enc, emb, nrm, vq, NROWS);

  // decoder
  deconv3x3<128, 64, 8, 32, 32, true>
      <<<N * 8 * 32 * 32 / 256, 256, 0, stream>>>(vq, dw1, db1, dd1, N);
  deconv3x3<64, 32, 8, 64, 64, true>
      <<<N * 4 * 64 * 64 / 256, 256, 0, stream>>>(dd1, dw2, db2, dd2, N);
  deconv3x3<32, 1, 1, 128, 128, false>
      <<<N * 1 * 128 * 128 / 256, 256, 0, stream>>>(dd2, dw3, db3, outp, N);
}

// Round 5
// 1108.805 us; speedup vs baseline: 2.6004x; 1.2497x over previous
//
#include <hip/hip_runtime.h>

// ---------------------------------------------------------------------------
// VQ-VAE forward (NCHW). Round 5: VQ distance GEMM -> MFMA split-bf16.
//  - conv4_mfma epilogue now writes enc directly as bf16 hi/lo (no fp32 enc).
//  - emb packed into B-fragment order (emb_prep); vq_mfma computes scores
//    with 6 MFMAs per 16-code tile, per-lane running argmin, shfl-xor
//    min-reduce (tie-break: smaller index), LDS idx, coalesced gather.
//  - R4 validated split-bf16 does not perturb the argmin (absmax unchanged).
// Everything else unchanged from R4.
// ---------------------------------------------------------------------------

using short8  = __attribute__((ext_vector_type(8))) short;
using floatx4 = __attribute__((ext_vector_type(4))) float;

__device__ inline unsigned short bf16rn(float f) {
  unsigned u = __float_as_uint(f);
  unsigned r = (u + 0x7fffu + ((u >> 16) & 1u)) >> 16;
  return (unsigned short)r;
}

// ------------------------- fp32 direct conv (R3) ---------------------------
template<int CIN, int COUT, int OCT, int H, int W, int S, bool RELU>
__global__ __launch_bounds__(256) void conv3x3(const float* __restrict__ in,
                                               const float* __restrict__ wgt,
                                               const float* __restrict__ bias,
                                               float* __restrict__ out, int N) {
  constexpr int OH = (S == 2) ? H / 2 : H;
  constexpr int OW = (S == 2) ? W / 2 : W;
  constexpr int TILES = COUT / OCT;
  int t = blockIdx.x * 256 + threadIdx.x;
  if (t >= N * TILES * OH * OW) return;
  const int ow = t % OW;
  int tmp = t / OW;
  const int oh = tmp % OH; tmp /= OH;
  const int tc = tmp % TILES;
  const int n  = tmp / TILES;
  const int oc0 = __builtin_amdgcn_readfirstlane(tc * OCT);

  const int ih0 = S * oh - 1, iw0 = S * ow - 1;
  float acc[OCT];
#pragma unroll
  for (int o = 0; o < OCT; ++o) acc[o] = bias[oc0 + o];

  const float* ip = in + (size_t)(n * CIN) * H * W;
  for (int ic = 0; ic < CIN; ++ic, ip += H * W) {
    float v[9];
#pragma unroll
    for (int kh = 0; kh < 3; ++kh) {
      const int ih = ih0 + kh;
#pragma unroll
      for (int kw = 0; kw < 3; ++kw) {
        const int iw = iw0 + kw;
        const bool ok = (ih >= 0) && (ih < H) && (iw >= 0) && (iw < W);
        v[kh * 3 + kw] = ok ? ip[ih * W + iw] : 0.f;
      }
    }
    const float* wp = wgt + ((oc0 * CIN + ic) * 9);
#pragma unroll
    for (int o = 0; o < OCT; ++o) {
      float s = acc[o];
#pragma unroll
      for (int k = 0; k < 9; ++k) s = fmaf(v[k], wp[o * CIN * 9 + k], s);
      acc[o] = s;
    }
  }
  float* op = out + ((size_t)(n * COUT + oc0) * OH + oh) * OW + ow;
#pragma unroll
  for (int o = 0; o < OCT; ++o) {
    float r = acc[o];
    if (RELU) r = fmaxf(r, 0.f);
    op[(size_t)o * OH * OW] = r;
  }
}

template<int CIN, int COUT, int OCT, int IH, int IW, bool RELU>
__global__ __launch_bounds__(256) void deconv3x3(const float* __restrict__ in,
                                                 const float* __restrict__ wgt,
                                                 const float* __restrict__ bias,
                                                 float* __restrict__ out, int N) {
  constexpr int OH = 2 * IH, OW = 2 * IW;
  constexpr int TILES = COUT / OCT;
  int t = blockIdx.x * 256 + threadIdx.x;
  if (t >= N * TILES * IH * IW) return;
  const int j = t % IW;
  int tmp = t / IW;
  const int i = tmp % IH; tmp /= IH;
  const int tc = tmp % TILES;
  const int n  = tmp / TILES;
  const int oc0 = __builtin_amdgcn_readfirstlane(tc * OCT);

  float a00[OCT], a01[OCT], a10[OCT], a11[OCT];
#pragma unroll
  for (int o = 0; o < OCT; ++o) {
    const float b = bias[oc0 + o];
    a00[o] = b; a01[o] = b; a10[o] = b; a11[o] = b;
  }
  const bool rg = (j + 1) < IW;
  const bool bg = (i + 1) < IH;

  const float* ip = in + ((size_t)(n * CIN) * IH + i) * IW + j;
  for (int ic = 0; ic < CIN; ++ic, ip += IH * IW) {
    const float x00 = ip[0];
    const float x01 = rg ? ip[1] : 0.f;
    const float x10 = bg ? ip[IW] : 0.f;
    const float x11 = (rg && bg) ? ip[IW + 1] : 0.f;
    const float* wp = wgt + (ic * COUT + oc0) * 9;
#pragma unroll
    for (int o = 0; o < OCT; ++o) {
      const float* wo = wp + o * 9;
      a00[o] = fmaf(x00, wo[4], a00[o]);
      a01[o] = fmaf(x00, wo[5], fmaf(x01, wo[3], a01[o]));
      a10[o] = fmaf(x00, wo[7], fmaf(x10, wo[1], a10[o]));
      a11[o] = fmaf(x00, wo[8], fmaf(x01, wo[6], fmaf(x10, wo[2], fmaf(x11, wo[0], a11[o]))));
    }
  }
  float* op = out + ((size_t)(n * COUT + oc0) * OH + 2 * i) * OW + 2 * j;
#pragma unroll
  for (int o = 0; o < OCT; ++o) {
    float r00 = a00[o], r01 = a01[o], r10 = a10[o], r11 = a11[o];
    if (RELU) {
      r00 = fmaxf(r00, 0.f); r01 = fmaxf(r01, 0.f);
      r10 = fmaxf(r10, 0.f); r11 = fmaxf(r11, 0.f);
    }
    float* q = op + (size_t)o * OH * OW;
    q[0] = r00; q[1] = r01; q[OW] = r10; q[OW + 1] = r11;
  }
}

// ------------------------------- VQ helpers --------------------------------
__global__ __launch_bounds__(256) void vq_norms(const float* __restrict__ emb,
                                                float* __restrict__ norms) {
  int jj = blockIdx.x * 256 + threadIdx.x;
  if (jj < 512) {
    float s = 0.f;
    const float* e = emb + jj * 64;
#pragma unroll
    for (int k = 0; k < 64; ++k) s = fmaf(e[k], e[k], s);
    norms[jj] = s;
  }
}

// Pack emb [512][64] fp32 into split-bf16 B-fragments.
// fi = ((ct*2 + kk)*64 + lane)*8 + j ; code = ct*16 + (lane&15),
// k = kk*32 + (lane>>4)*8 + j.
__global__ __launch_bounds__(256) void emb_prep(const float* __restrict__ emb,
                                                short* __restrict__ hi,
                                                short* __restrict__ lo) {
  const int t = blockIdx.x * 256 + threadIdx.x;  // < 32*2*64*8 = 32768
  const int j  = t & 7;
  const int l  = (t >> 3) & 63;
  const int kk = (t >> 9) & 1;
  const int ct = t >> 10;
  const int code = ct * 16 + (l & 15);
  const int k = kk * 32 + ((l >> 4) << 3) + j;
  const float v = emb[code * 64 + k];
  const unsigned short h = bf16rn(v);
  hi[t] = (short)h;
  lo[t] = (short)bf16rn(v - __uint_as_float((unsigned)h << 16));
}

// GEMM-based VQ: wave handles 16 rows; loop 32 code-tiles; score =
// |e|^2 - 2 f.e via 6 split-bf16 MFMAs; running argmin in D layout;
// shfl-xor min-reduce over 16 cols (tie-break smaller idx); gather emb[idx].
__global__ __launch_bounds__(256) void vq_mfma(
    const short* __restrict__ fhi, const short* __restrict__ flo,
    const short* __restrict__ ebh, const short* __restrict__ ebl,
    const float* __restrict__ nrm, const float* __restrict__ emb,
    float* __restrict__ out) {
  __shared__ int sidx[64];
  const int lane = threadIdx.x & 63;
  const int wave = threadIdx.x >> 6;
  const int r0 = blockIdx.x * 64 + wave * 16;
  // A[m=lane&15][k=(lane>>4)*8+j], kk adds 32
  const size_t abase = ((size_t)(r0 + (lane & 15))) * 64 + ((lane >> 4) << 3);
  short8 ah0 = *(const short8*)(fhi + abase);
  short8 ah1 = *(const short8*)(fhi + abase + 32);
  short8 al0 = *(const short8*)(flo + abase);
  short8 al1 = *(const short8*)(flo + abase + 32);

  float bestv[4] = {3.4e38f, 3.4e38f, 3.4e38f, 3.4e38f};
  int   besti[4] = {0, 0, 0, 0};
  const short8* __restrict__ ebh8 = (const short8*)ebh;
  const short8* __restrict__ ebl8 = (const short8*)ebl;
  for (int ct = 0; ct < 32; ++ct) {
    const int f0 = (ct * 2) * 64 + lane;
    const short8 b0h = ebh8[f0];
    const short8 b1h = ebh8[f0 + 64];
    const short8 b0l = ebl8[f0];
    const short8 b1l = ebl8[f0 + 64];
    floatx4 acc = {0.f, 0.f, 0.f, 0.f};
    acc = __builtin_amdgcn_mfma_f32_16x16x32_bf16(ah0, b0h, acc, 0, 0, 0);
    acc = __builtin_amdgcn_mfma_f32_16x16x32_bf16(ah1, b1h, acc, 0, 0, 0);
    acc = __builtin_amdgcn_mfma_f32_16x16x32_bf16(ah0, b0l, acc, 0, 0, 0);
    acc = __builtin_amdgcn_mfma_f32_16x16x32_bf16(ah1, b1l, acc, 0, 0, 0);
    acc = __builtin_amdgcn_mfma_f32_16x16x32_bf16(al0, b0h, acc, 0, 0, 0);
    acc = __builtin_amdgcn_mfma_f32_16x16x32_bf16(al1, b1h, acc, 0, 0, 0);
    const int code = ct * 16 + (lane & 15);
    const float nn = nrm[code];
#pragma unroll
    for (int q = 0; q < 4; ++q) {
      const float sc = nn - 2.f * acc[q];
      if (sc < bestv[q]) { bestv[q] = sc; besti[q] = code; }  // codes ascend
    }
  }
#pragma unroll
  for (int off = 1; off < 16; off <<= 1) {
#pragma unroll
    for (int q = 0; q < 4; ++q) {
      const float ov = __shfl_xor(bestv[q], off, 64);
      const int   oi = __shfl_xor(besti[q], off, 64);
      if (ov < bestv[q] || (ov == bestv[q] && oi < besti[q])) {
        bestv[q] = ov; besti[q] = oi;
      }
    }
  }
  if ((lane & 15) == 0) {
#pragma unroll
    for (int q = 0; q < 4; ++q)
      sidx[wave * 16 + (lane >> 4) * 4 + q] = besti[q];
  }
  __syncthreads();
  // gather: 64 rows x 64 floats, 4 threads/row, coalesced float4 writes
  const int row  = threadIdx.x >> 2;
  const int part = threadIdx.x & 3;
  const int gi = sidx[row];
  const float4* src = (const float4*)(emb + (size_t)gi * 64 + part * 16);
  float4* dst = (float4*)(out + ((size_t)blockIdx.x * 64 + row) * 64 + part * 16);
  dst[0] = src[0]; dst[1] = src[1]; dst[2] = src[2]; dst[3] = src[3];
}

// ----------------------- conv4 MFMA path (R4) ------------------------------
__global__ __launch_bounds__(256) void w4_prep(const float* __restrict__ w,
                                               short* __restrict__ hi,
                                               short* __restrict__ lo) {
  const int t = blockIdx.x * 256 + threadIdx.x;  // < 36*8*64*8 = 147456
  const int j  = t & 7;
  const int l  = (t >> 3) & 63;
  const int mt = (t >> 9) & 7;
  const int s  = t >> 12;
  const int icb = s / 9, tap = s - icb * 9;
  const int kh = tap / 3, kw = tap - kh * 3;
  const int m  = mt * 16 + (l & 15);
  const int ic = icb * 32 + ((l >> 4) & 3) * 8 + j;
  const float v = w[((m * 128 + ic) * 3 + kh) * 3 + kw];
  const unsigned short h = bf16rn(v);
  hi[t] = (short)h;
  lo[t] = (short)bf16rn(v - __uint_as_float((unsigned)h << 16));
}

__global__ __launch_bounds__(256) void xt_prep(const float* __restrict__ x,
                                               short* __restrict__ hi,
                                               short* __restrict__ lo, int total) {
  const int t = blockIdx.x * 256 + threadIdx.x;
  if (t >= total) return;                 // total = N*34*34*128
  const int ic = t & 127;
  int pp = t >> 7;
  const int cc = pp % 34; pp /= 34;
  const int rr = pp % 34;
  const int n  = pp / 34;
  const int r = rr - 1, c = cc - 1;
  float v = 0.f;
  if (r >= 0 && r < 32 && c >= 0 && c < 32)
    v = x[(((size_t)n * 128 + ic) * 32 + r) * 32 + c];
  const unsigned short h = bf16rn(v);
  hi[t] = (short)h;
  lo[t] = (short)bf16rn(v - __uint_as_float((unsigned)h << 16));
}

// conv4 implicit GEMM; epilogue writes enc as bf16 hi/lo (feeds vq_mfma).
__global__ __launch_bounds__(256) void conv4_mfma(
    const short* __restrict__ xthi, const short* __restrict__ xtlo,
    const short* __restrict__ ahi,  const short* __restrict__ alo,
    const float* __restrict__ bias,
    short* __restrict__ ench, short* __restrict__ encl) {
  const int b    = blockIdx.x;
  const int n    = b >> 4;
  const int pt   = b & 15;
  const int lane = threadIdx.x & 63;
  const int wave = threadIdx.x >> 6;
  const int pl   = wave * 16 + (lane & 15);
  const int r    = 2 * pt + (pl >> 5);
  const int c    = pl & 31;
  const int kq   = lane >> 4;

  floatx4 acc[8];
#pragma unroll
  for (int mt = 0; mt < 8; ++mt) acc[mt] = (floatx4){0.f, 0.f, 0.f, 0.f};

  const size_t bbase = (((size_t)n * 34 + r) * 34 + c) * 128 + kq * 8;
  const short8* __restrict__ ah8 = (const short8*)ahi;
  const short8* __restrict__ al8 = (const short8*)alo;

  int s = 0;
  for (int icb = 0; icb < 4; ++icb) {
#pragma unroll
    for (int tap = 0; tap < 9; ++tap, ++s) {
      const int kh = tap / 3, kw = tap - kh * 3;
      const size_t be = bbase + (size_t)(kh * 34 + kw) * 128 + icb * 32;
      const short8 bh = *(const short8*)(xthi + be);
      const short8 bl = *(const short8*)(xtlo + be);
#pragma unroll
      for (int mt = 0; mt < 8; ++mt) {
        const int fi = ((s * 8 + mt) << 6) + lane;
        const short8 ah = ah8[fi];
        const short8 al = al8[fi];
        acc[mt] = __builtin_amdgcn_mfma_f32_16x16x32_bf16(ah, bh, acc[mt], 0, 0, 0);
        acc[mt] = __builtin_amdgcn_mfma_f32_16x16x32_bf16(ah, bl, acc[mt], 0, 0, 0);
        acc[mt] = __builtin_amdgcn_mfma_f32_16x16x32_bf16(al, bh, acc[mt], 0, 0, 0);
      }
    }
  }

  const size_t obase = (size_t)n * 128 * 1024 + (pt * 64 + pl);
#pragma unroll
  for (int mt = 0; mt < 8; ++mt) {
#pragma unroll
    for (int q = 0; q < 4; ++q) {
      const int cout = mt * 16 + kq * 4 + q;
      const float rr = fmaxf(acc[mt][q] + bias[cout], 0.f);
      const unsigned short h = bf16rn(rr);
      const size_t oi = obase + (size_t)cout * 1024;
      ench[oi] = (short)h;
      encl[oi] = (short)bf16rn(rr - __uint_as_float((unsigned)h << 16));
    }
  }
}

// ---------------------------------------------------------------------------
extern "C" void kernel_launch(void* const* d_in, const int* in_sizes, int n_in,
                              void* d_out, int out_size, void* d_ws, size_t ws_size,
                              hipStream_t stream) {
  const float* x   = (const float*)d_in[0];
  const float* w1  = (const float*)d_in[1];
  const float* b1  = (const float*)d_in[2];
  const float* w2  = (const float*)d_in[3];
  const float* b2  = (const float*)d_in[4];
  const float* w3  = (const float*)d_in[5];
  const float* b3  = (const float*)d_in[6];
  const float* w4  = (const float*)d_in[7];
  const float* b4  = (const float*)d_in[8];
  const float* emb = (const float*)d_in[9];
  const float* dw1 = (const float*)d_in[10];
  const float* db1 = (const float*)d_in[11];
  const float* dw2 = (const float*)d_in[12];
  const float* db2 = (const float*)d_in[13];
  const float* dw3 = (const float*)d_in[14];
  const float* db3 = (const float*)d_in[15];
  float* outp = (float*)d_out;

  const int N = in_sizes[0] / (2 * 256 * 256);  // 64

  const size_t F_H1 = (size_t)N * 32 * 128 * 128;
  const size_t F_H2 = (size_t)N * 64 * 64 * 64;
  const size_t F_H3 = (size_t)N * 128 * 32 * 32;
  const size_t AFRAG = 36 * 8 * 64 * 8;            // shorts per split
  const size_t XTOT  = (size_t)N * 34 * 34 * 128;  // shorts per split
  const size_t need_bytes = (F_H1 + F_H2 + 512 + AFRAG) * sizeof(float);
  if (ws_size < need_bytes) return;

  float* ws  = (float*)d_ws;
  float* h1  = ws;               // conv1 out           [0, F_H1)
  float* h2  = ws + F_H1;        // conv2 out           [F_H1, +F_H2)
  float* h3  = ws;               // conv3 out (reuse h1)[0, F_H3)
  // inside dead h1 region, beyond h3:
  short* xthi = (short*)(ws + F_H3);                  // XTOT shorts
  short* xtlo = xthi + XTOT;                          // XTOT shorts
  short* ench = (short*)(ws + F_H3 + XTOT);           // F_H3 shorts
  short* encl = ench + F_H3;                          // F_H3 shorts
  short* ebh  = (short*)(ws + 2 * F_H3 + XTOT);       // 32768 shorts
  short* ebl  = ebh + 32768;                          // 32768 shorts
  float* vq   = ws;              // VQ out (reuse h3)   [0, F_H3)
  float* dd1  = ws + F_H1;       // dec1 out (reuse h2)
  float* dd2  = ws;              // dec2 out
  float* nrm  = ws + F_H1 + F_H2;
  short* ahi  = (short*)(ws + F_H1 + F_H2 + 512);
  short* alo  = ahi + AFRAG;

  // encoder
  conv3x3<2, 32, 16, 256, 256, 2, true>
      <<<N * 2 * 128 * 128 / 256, 256, 0, stream>>>(x, w1, b1, h1, N);
  conv3x3<32, 64, 16, 128, 128, 2, true>
      <<<N * 4 * 64 * 64 / 256, 256, 0, stream>>>(h1, w2, b2, h2, N);
  conv3x3<64, 128, 16, 64, 64, 2, true>
      <<<N * 8 * 32 * 32 / 256, 256, 0, stream>>>(h2, w3, b3, h3, N);

  // conv4 via MFMA split-bf16 (enc emitted as bf16 hi/lo)
  w4_prep<<<(int)(AFRAG / 256), 256, 0, stream>>>(w4, ahi, alo);
  xt_prep<<<(int)((XTOT + 255) / 256), 256, 0, stream>>>(h3, xthi, xtlo, (int)XTOT);
  conv4_mfma<<<N * 16, 256, 0, stream>>>(xthi, xtlo, ahi, alo, b4, ench, encl);

  // VQ via MFMA
  vq_norms<<<2, 256, 0, stream>>>(emb, nrm);
  emb_prep<<<128, 256, 0, stream>>>(emb, ebh, ebl);
  vq_mfma<<<(int)(F_H3 / 64 / 64), 256, 0, stream>>>(ench, encl, ebh, ebl, nrm, emb, vq);

  // decoder
  deconv3x3<128, 64, 8, 32, 32, true>
      <<<N * 8 * 32 * 32 / 256, 256, 0, stream>>>(vq, dw1, db1, dd1, N);
  deconv3x3<64, 32, 8, 64, 64, true>
      <<<N * 4 * 64 * 64 / 256, 256, 0, stream>>>(dd1, dw2, db2, dd2, N);
  deconv3x3<32, 1, 1, 128, 128, false>
      <<<N * 1 * 128 * 128 / 256, 256, 0, stream>>>(dd2, dw3, db3, outp, N);
}

// Round 6
// 988.193 us; speedup vs baseline: 2.9178x; 1.1221x over previous
//
#include <hip/hip_runtime.h>

// ---------------------------------------------------------------------------
// VQ-VAE forward (NCHW). Round 6: full MFMA conversion.
//  All activations in padded-NHWC bf16 split hi/lo "xt" format:
//    xt[n][PH][PW][C], pad ring of 1 (zeroed per call).
//  conv1: fp32 direct (K=18 too small for MFMA), writes xt.
//  conv2/conv3: generic stride-2 implicit-GEMM MFMA (split-bf16, 3 products).
//  conv4: R4/R5 proven kernel (unchanged), writes flat bf16 enc for VQ.
//  VQ: R5 proven MFMA scoring; gather now writes xt for dec1.
//  dec1/dec2: transposed conv as 4-phase implicit-GEMM MFMA (tap tables).
//  dec3: fp32 VALU direct from split-bf16 input (COUT=1).
//  Arena liveness-packed: peak 182.1 MB (< 201.4 MB known-good ws_size).
//  conv1->conv2 and dec2->dec3 run in two batch halves (130x130 bufs halved).
// ---------------------------------------------------------------------------

using short8  = __attribute__((ext_vector_type(8))) short;
using short4v = __attribute__((ext_vector_type(4))) short;
using floatx4 = __attribute__((ext_vector_type(4))) float;

__device__ inline unsigned short bf16rn(float f) {
  unsigned u = __float_as_uint(f);
  unsigned r = (u + 0x7fffu + ((u >> 16) & 1u)) >> 16;
  return (unsigned short)r;
}
__device__ inline float bf2f(short h, short l) {
  return __uint_as_float(((unsigned)(unsigned short)h) << 16) +
         __uint_as_float(((unsigned)(unsigned short)l) << 16);
}

// ---- deconv phase tap tables: entry e -> (ky,kx) weight tap, (di,dj) input
// phase order ph0=(0,0) ph1=(0,1) ph2=(1,0) ph3=(1,1); DOFF = entry ranges.
__device__ const int DKY[9]  = {1, 1, 1, 2, 0, 2, 2, 0, 0};
__device__ const int DKX[9]  = {1, 2, 0, 1, 1, 2, 0, 2, 0};
__device__ const int DDI[9]  = {0, 0, 0, 0, 1, 0, 0, 1, 1};
__device__ const int DDJ[9]  = {0, 0, 1, 0, 0, 0, 1, 0, 1};
__device__ const int DOFF[5] = {0, 1, 3, 5, 9};

// ---------------- ring zero: clear pad ring of xt buffer ------------------
__global__ __launch_bounds__(256) void ring_zero(short* __restrict__ h,
                                                 short* __restrict__ l,
                                                 int nimg, int PH, int PW, int C) {
  const int RC = (2 * PW + 2 * (PH - 2)) * C;
  int t = blockIdx.x * 256 + threadIdx.x;
  if (t >= nimg * RC) return;
  const int nl = t / RC;
  int rem = t - nl * RC;
  const int p = rem / C;
  const int ch = rem - p * C;
  int r, c;
  if (p < 2 * PW) {
    r = (p < PW) ? 0 : PH - 1;
    c = (p < PW) ? p : p - PW;
  } else {
    int q = p - 2 * PW;
    if (q < PH - 2) { r = 1 + q; c = 0; }
    else { r = 1 + q - (PH - 2); c = PW - 1; }
  }
  const size_t a = (((size_t)nl * PH + r) * PW + c) * C + ch;
  h[a] = 0; l[a] = 0;
}

// ---------------- conv1: fp32 direct, writes xt [nh][130][130][32] --------
__global__ __launch_bounds__(256) void conv1_xt(const float* __restrict__ x,
                                                const float* __restrict__ w,
                                                const float* __restrict__ bias,
                                                short* __restrict__ oh,
                                                short* __restrict__ ol, int NH) {
  int t = blockIdx.x * 256 + threadIdx.x;
  if (t >= NH * 128 * 128) return;
  const int px = t & 16383;
  const int n  = t >> 14;
  const int r = px >> 7, c = px & 127;
  const int ih0 = 2 * r - 1, iw0 = 2 * c - 1;
  float acc[32];
#pragma unroll
  for (int o = 0; o < 32; ++o) acc[o] = bias[o];
  const float* ip = x + (size_t)n * 2 * 65536;
#pragma unroll
  for (int ic = 0; ic < 2; ++ic, ip += 65536) {
    float v[9];
#pragma unroll
    for (int kh = 0; kh < 3; ++kh) {
      const int ih = ih0 + kh;
#pragma unroll
      for (int kw = 0; kw < 3; ++kw) {
        const int iw = iw0 + kw;
        const bool ok = (ih >= 0) && (ih < 256) && (iw >= 0) && (iw < 256);
        v[kh * 3 + kw] = ok ? ip[ih * 256 + iw] : 0.f;
      }
    }
#pragma unroll
    for (int o = 0; o < 32; ++o) {
      float s = acc[o];
#pragma unroll
      for (int k = 0; k < 9; ++k) s = fmaf(v[k], w[(o * 2 + ic) * 9 + k], s);
      acc[o] = s;
    }
  }
  const size_t base = (((size_t)n * 130 + r + 1) * 130 + (c + 1)) * 32;
  short8 vh[4], vl[4];
#pragma unroll
  for (int g = 0; g < 4; ++g) {
#pragma unroll
    for (int kk = 0; kk < 8; ++kk) {
      const float rv = fmaxf(acc[g * 8 + kk], 0.f);
      const unsigned short hh = bf16rn(rv);
      vh[g][kk] = (short)hh;
      vl[g][kk] = (short)bf16rn(rv - __uint_as_float((unsigned)hh << 16));
    }
    *(short8*)(oh + base + g * 8) = vh[g];
    *(short8*)(ol + base + g * 8) = vl[g];
  }
}

// ---------------- generic A-frag prep: conv weights [COUT][CIN][3][3] -----
template<int CIN, int COUT>
__global__ __launch_bounds__(256) void wprep_conv(const float* __restrict__ w,
                                                  short* __restrict__ hi,
                                                  short* __restrict__ lo) {
  constexpr int MT = COUT / 16;
  const int t = blockIdx.x * 256 + threadIdx.x;  // < (CIN/32)*9*MT*512
  const int j = t & 7;
  const int lane = (t >> 3) & 63;
  const int g = t >> 9;
  const int mt = g % MT;
  const int s = g / MT;
  const int icb = s / 9, tap = s - icb * 9;
  const int kh = tap / 3, kw = tap - kh * 3;
  const int m = mt * 16 + (lane & 15);
  const int ic = icb * 32 + ((lane >> 4) << 3) + j;
  const float v = w[((m * CIN + ic) * 3 + kh) * 3 + kw];
  const unsigned short h = bf16rn(v);
  hi[t] = (short)h;
  lo[t] = (short)bf16rn(v - __uint_as_float((unsigned)h << 16));
}

// ---------------- deconv A-frag prep: weights [CIN][COUT][3][3] -----------
template<int CIN, int COUT>
__global__ __launch_bounds__(256) void wprep_dec(const float* __restrict__ w,
                                                 short* __restrict__ hi,
                                                 short* __restrict__ lo) {
  constexpr int MT = COUT / 16, ICB = CIN / 32;
  const int t = blockIdx.x * 256 + threadIdx.x;  // < 9*ICB*MT*512
  const int j = t & 7;
  const int lane = (t >> 3) & 63;
  const int g = t >> 9;
  const int mt = g % MT;
  const int u = g / MT;
  const int icb = u % ICB;
  const int e = u / ICB;
  const int ky = DKY[e], kx = DKX[e];
  const int m = mt * 16 + (lane & 15);
  const int ic = icb * 32 + ((lane >> 4) << 3) + j;
  const float v = w[((ic * COUT + m) * 3 + ky) * 3 + kx];
  const unsigned short h = bf16rn(v);
  hi[t] = (short)h;
  lo[t] = (short)bf16rn(v - __uint_as_float((unsigned)h << 16));
}

// ---------------- generic strided conv MFMA (xt in -> xt out, relu) -------
template<int CIN, int COUT, int OH, int OW, int S, int PHI, int PWI, int PHO, int PWO>
__global__ __launch_bounds__(256) void conv_mfma_xt(
    const short* __restrict__ xih, const short* __restrict__ xil,
    const short* __restrict__ ah,  const short* __restrict__ al,
    const float* __restrict__ bias,
    short* __restrict__ xoh, short* __restrict__ xol) {
  constexpr int MT = COUT / 16, ICB = CIN / 32, TPB = OH * OW / 64;
  const int b = blockIdx.x;
  const int n = b / TPB, pt = b % TPB;
  const int lane = threadIdx.x & 63, wave = threadIdx.x >> 6;
  const int pl = pt * 64 + wave * 16 + (lane & 15);
  const int r = pl / OW, c = pl % OW;
  const int quad = lane >> 4;

  floatx4 acc[MT];
#pragma unroll
  for (int mt = 0; mt < MT; ++mt) acc[mt] = (floatx4){0.f, 0.f, 0.f, 0.f};

  const size_t bbase = (((size_t)n * PHI + S * r) * PWI + S * c) * CIN + quad * 8;
  const short8* __restrict__ ah8 = (const short8*)ah;
  const short8* __restrict__ al8 = (const short8*)al;

  for (int icb = 0; icb < ICB; ++icb) {
#pragma unroll
    for (int tap = 0; tap < 9; ++tap) {
      const int kh = tap / 3, kw = tap - kh * 3;
      const size_t be = bbase + (size_t)(kh * PWI + kw) * CIN + icb * 32;
      const short8 bh = *(const short8*)(xih + be);
      const short8 bl = *(const short8*)(xil + be);
#pragma unroll
      for (int mt = 0; mt < MT; ++mt) {
        const int fi = ((icb * 9 + tap) * MT + mt) * 64 + lane;
        const short8 wh = ah8[fi];
        const short8 wl = al8[fi];
        acc[mt] = __builtin_amdgcn_mfma_f32_16x16x32_bf16(wh, bh, acc[mt], 0, 0, 0);
        acc[mt] = __builtin_amdgcn_mfma_f32_16x16x32_bf16(wh, bl, acc[mt], 0, 0, 0);
        acc[mt] = __builtin_amdgcn_mfma_f32_16x16x32_bf16(wl, bh, acc[mt], 0, 0, 0);
      }
    }
  }
  const size_t ob = (((size_t)n * PHO + r + 1) * PWO + (c + 1)) * COUT + quad * 4;
#pragma unroll
  for (int mt = 0; mt < MT; ++mt) {
    short4v sh, sl;
#pragma unroll
    for (int q = 0; q < 4; ++q) {
      const float v = fmaxf(acc[mt][q] + bias[mt * 16 + quad * 4 + q], 0.f);
      const unsigned short hh = bf16rn(v);
      sh[q] = (short)hh;
      sl[q] = (short)bf16rn(v - __uint_as_float((unsigned)hh << 16));
    }
    *(short4v*)(xoh + ob + mt * 16) = sh;
    *(short4v*)(xol + ob + mt * 16) = sl;
  }
}

// ---------------- 4-phase transposed conv MFMA (xt -> xt, relu) -----------
template<int CIN, int COUT, int IH, int IW, int PHI, int PWI, int PHO, int PWO>
__global__ __launch_bounds__(256) void deconv_mfma_xt(
    const short* __restrict__ xih, const short* __restrict__ xil,
    const short* __restrict__ ah,  const short* __restrict__ al,
    const float* __restrict__ bias,
    short* __restrict__ xoh, short* __restrict__ xol) {
  constexpr int MT = COUT / 16, ICB = CIN / 32, TPB = IH * IW / 64;
  const int ph = blockIdx.x & 3;
  const int bb = blockIdx.x >> 2;
  const int n = bb / TPB, pt = bb % TPB;
  const int lane = threadIdx.x & 63, wave = threadIdx.x >> 6;
  const int pl = pt * 64 + wave * 16 + (lane & 15);
  const int i = pl / IW, j = pl % IW;
  const int quad = lane >> 4;

  floatx4 acc[MT];
#pragma unroll
  for (int mt = 0; mt < MT; ++mt) acc[mt] = (floatx4){0.f, 0.f, 0.f, 0.f};

  const short8* __restrict__ ah8 = (const short8*)ah;
  const short8* __restrict__ al8 = (const short8*)al;
  const int e0 = DOFF[ph], e1 = DOFF[ph + 1];
  for (int e = e0; e < e1; ++e) {
    const int di = DDI[e], dj = DDJ[e];
    const size_t pb = (((size_t)n * PHI + (i + 1 + di)) * PWI + (j + 1 + dj)) * CIN + quad * 8;
    for (int icb = 0; icb < ICB; ++icb) {
      const size_t be = pb + icb * 32;
      const short8 bh = *(const short8*)(xih + be);
      const short8 bl = *(const short8*)(xil + be);
#pragma unroll
      for (int mt = 0; mt < MT; ++mt) {
        const int fi = ((e * ICB + icb) * MT + mt) * 64 + lane;
        const short8 wh = ah8[fi];
        const short8 wl = al8[fi];
        acc[mt] = __builtin_amdgcn_mfma_f32_16x16x32_bf16(wh, bh, acc[mt], 0, 0, 0);
        acc[mt] = __builtin_amdgcn_mfma_f32_16x16x32_bf16(wh, bl, acc[mt], 0, 0, 0);
        acc[mt] = __builtin_amdgcn_mfma_f32_16x16x32_bf16(wl, bh, acc[mt], 0, 0, 0);
      }
    }
  }
  const int oy = 2 * i + (ph >> 1), ox = 2 * j + (ph & 1);
  const size_t ob = (((size_t)n * PHO + oy + 1) * PWO + (ox + 1)) * COUT + quad * 4;
#pragma unroll
  for (int mt = 0; mt < MT; ++mt) {
    short4v sh, sl;
#pragma unroll
    for (int q = 0; q < 4; ++q) {
      const float v = fmaxf(acc[mt][q] + bias[mt * 16 + quad * 4 + q], 0.f);
      const unsigned short hh = bf16rn(v);
      sh[q] = (short)hh;
      sl[q] = (short)bf16rn(v - __uint_as_float((unsigned)hh << 16));
    }
    *(short4v*)(xoh + ob + mt * 16) = sh;
    *(short4v*)(xol + ob + mt * 16) = sl;
  }
}

// ---------------- conv4 MFMA (R4/R5 proven, unchanged) --------------------
__global__ __launch_bounds__(256) void conv4_mfma(
    const short* __restrict__ xthi, const short* __restrict__ xtlo,
    const short* __restrict__ ahi,  const short* __restrict__ alo,
    const float* __restrict__ bias,
    short* __restrict__ ench, short* __restrict__ encl) {
  const int b    = blockIdx.x;
  const int n    = b >> 4;
  const int pt   = b & 15;
  const int lane = threadIdx.x & 63;
  const int wave = threadIdx.x >> 6;
  const int pl   = wave * 16 + (lane & 15);
  const int r    = 2 * pt + (pl >> 5);
  const int c    = pl & 31;
  const int kq   = lane >> 4;

  floatx4 acc[8];
#pragma unroll
  for (int mt = 0; mt < 8; ++mt) acc[mt] = (floatx4){0.f, 0.f, 0.f, 0.f};

  const size_t bbase = (((size_t)n * 34 + r) * 34 + c) * 128 + kq * 8;
  const short8* __restrict__ ah8 = (const short8*)ahi;
  const short8* __restrict__ al8 = (const short8*)alo;

  int s = 0;
  for (int icb = 0; icb < 4; ++icb) {
#pragma unroll
    for (int tap = 0; tap < 9; ++tap, ++s) {
      const int kh = tap / 3, kw = tap - kh * 3;
      const size_t be = bbase + (size_t)(kh * 34 + kw) * 128 + icb * 32;
      const short8 bh = *(const short8*)(xthi + be);
      const short8 bl = *(const short8*)(xtlo + be);
#pragma unroll
      for (int mt = 0; mt < 8; ++mt) {
        const int fi = ((s * 8 + mt) << 6) + lane;
        const short8 ah = ah8[fi];
        const short8 al = al8[fi];
        acc[mt] = __builtin_amdgcn_mfma_f32_16x16x32_bf16(ah, bh, acc[mt], 0, 0, 0);
        acc[mt] = __builtin_amdgcn_mfma_f32_16x16x32_bf16(ah, bl, acc[mt], 0, 0, 0);
        acc[mt] = __builtin_amdgcn_mfma_f32_16x16x32_bf16(al, bh, acc[mt], 0, 0, 0);
      }
    }
  }
  const size_t obase = (size_t)n * 128 * 1024 + (pt * 64 + pl);
#pragma unroll
  for (int mt = 0; mt < 8; ++mt) {
#pragma unroll
    for (int q = 0; q < 4; ++q) {
      const int cout = mt * 16 + kq * 4 + q;
      const float rr = fmaxf(acc[mt][q] + bias[cout], 0.f);
      const unsigned short h = bf16rn(rr);
      const size_t oi = obase + (size_t)cout * 1024;
      ench[oi] = (short)h;
      encl[oi] = (short)bf16rn(rr - __uint_as_float((unsigned)h << 16));
    }
  }
}

// ------------------------------- VQ ---------------------------------------
__global__ __launch_bounds__(256) void vq_norms(const float* __restrict__ emb,
                                                float* __restrict__ norms) {
  int jj = blockIdx.x * 256 + threadIdx.x;
  if (jj < 512) {
    float s = 0.f;
    const float* e = emb + jj * 64;
#pragma unroll
    for (int k = 0; k < 64; ++k) s = fmaf(e[k], e[k], s);
    norms[jj] = s;
  }
}

__global__ __launch_bounds__(256) void emb_prep(const float* __restrict__ emb,
                                                short* __restrict__ hi,
                                                short* __restrict__ lo) {
  const int t = blockIdx.x * 256 + threadIdx.x;  // < 32768
  const int j  = t & 7;
  const int l  = (t >> 3) & 63;
  const int kk = (t >> 9) & 1;
  const int ct = t >> 10;
  const int code = ct * 16 + (l & 15);
  const int k = kk * 32 + ((l >> 4) << 3) + j;
  const float v = emb[code * 64 + k];
  const unsigned short h = bf16rn(v);
  hi[t] = (short)h;
  lo[t] = (short)bf16rn(v - __uint_as_float((unsigned)h << 16));
}

// R5 proven scoring; gather tail now writes xt [n][34][34][128] for dec1.
__global__ __launch_bounds__(256) void vq_mfma(
    const short* __restrict__ fhi, const short* __restrict__ flo,
    const short* __restrict__ ebh, const short* __restrict__ ebl,
    const float* __restrict__ nrm, const float* __restrict__ emb,
    short* __restrict__ d1h, short* __restrict__ d1l) {
  __shared__ int sidx[64];
  const int lane = threadIdx.x & 63;
  const int wave = threadIdx.x >> 6;
  const int r0 = blockIdx.x * 64 + wave * 16;
  const size_t abase = ((size_t)(r0 + (lane & 15))) * 64 + ((lane >> 4) << 3);
  short8 ah0 = *(const short8*)(fhi + abase);
  short8 ah1 = *(const short8*)(fhi + abase + 32);
  short8 al0 = *(const short8*)(flo + abase);
  short8 al1 = *(const short8*)(flo + abase + 32);

  float bestv[4] = {3.4e38f, 3.4e38f, 3.4e38f, 3.4e38f};
  int   besti[4] = {0, 0, 0, 0};
  const short8* __restrict__ ebh8 = (const short8*)ebh;
  const short8* __restrict__ ebl8 = (const short8*)ebl;
  for (int ct = 0; ct < 32; ++ct) {
    const int f0 = (ct * 2) * 64 + lane;
    const short8 b0h = ebh8[f0];
    const short8 b1h = ebh8[f0 + 64];
    const short8 b0l = ebl8[f0];
    const short8 b1l = ebl8[f0 + 64];
    floatx4 acc = {0.f, 0.f, 0.f, 0.f};
    acc = __builtin_amdgcn_mfma_f32_16x16x32_bf16(ah0, b0h, acc, 0, 0, 0);
    acc = __builtin_amdgcn_mfma_f32_16x16x32_bf16(ah1, b1h, acc, 0, 0, 0);
    acc = __builtin_amdgcn_mfma_f32_16x16x32_bf16(ah0, b0l, acc, 0, 0, 0);
    acc = __builtin_amdgcn_mfma_f32_16x16x32_bf16(ah1, b1l, acc, 0, 0, 0);
    acc = __builtin_amdgcn_mfma_f32_16x16x32_bf16(al0, b0h, acc, 0, 0, 0);
    acc = __builtin_amdgcn_mfma_f32_16x16x32_bf16(al1, b1h, acc, 0, 0, 0);
    const int code = ct * 16 + (lane & 15);
    const float nn = nrm[code];
#pragma unroll
    for (int q = 0; q < 4; ++q) {
      const float sc = nn - 2.f * acc[q];
      if (sc < bestv[q]) { bestv[q] = sc; besti[q] = code; }
    }
  }
#pragma unroll
  for (int off = 1; off < 16; off <<= 1) {
#pragma unroll
    for (int q = 0; q < 4; ++q) {
      const float ov = __shfl_xor(bestv[q], off, 64);
      const int   oi = __shfl_xor(besti[q], off, 64);
      if (ov < bestv[q] || (ov == bestv[q] && oi < besti[q])) {
        bestv[q] = ov; besti[q] = oi;
      }
    }
  }
  if ((lane & 15) == 0) {
#pragma unroll
    for (int q = 0; q < 4; ++q)
      sidx[wave * 16 + (lane >> 4) * 4 + q] = besti[q];
  }
  __syncthreads();
  // scatter emb[idx] into xt layout: rid -> (n, ch, pixblock)
  const int row  = threadIdx.x >> 2;
  const int part = threadIdx.x & 3;
  const int rid = blockIdx.x * 64 + row;
  const int n  = rid >> 11;
  const int ch = (rid >> 4) & 127;
  const int pb = rid & 15;
  const int gi = sidx[row];
  const float4* src = (const float4*)(emb + (size_t)gi * 64 + part * 16);
  float4 v0 = src[0], v1 = src[1], v2 = src[2], v3 = src[3];
  float vals[16] = {v0.x, v0.y, v0.z, v0.w, v1.x, v1.y, v1.z, v1.w,
                    v2.x, v2.y, v2.z, v2.w, v3.x, v3.y, v3.z, v3.w};
#pragma unroll
  for (int kk = 0; kk < 16; ++kk) {
    const int k = part * 16 + kk;
    const int pix = pb * 64 + k;
    const int r = pix >> 5, c = pix & 31;
    const size_t a = (((size_t)n * 34 + r + 1) * 34 + (c + 1)) * 128 + ch;
    const unsigned short h = bf16rn(vals[kk]);
    d1h[a] = (short)h;
    d1l[a] = (short)bf16rn(vals[kk] - __uint_as_float((unsigned)h << 16));
  }
}

// ---------------- dec3: fp32 direct from split-bf16 xt input --------------
__global__ __launch_bounds__(256) void dec3_xt(const short* __restrict__ xh,
                                               const short* __restrict__ xl,
                                               const float* __restrict__ w,
                                               const float* __restrict__ bias,
                                               float* __restrict__ out, int NH) {
  int t = blockIdx.x * 256 + threadIdx.x;
  if (t >= NH * 128 * 128) return;
  const int px = t & 16383;
  const int nl = t >> 14;
  const int i = px >> 7, j = px & 127;
  const float b0 = bias[0];
  float a00 = b0, a01 = b0, a10 = b0, a11 = b0;
  const size_t base00 = (((size_t)nl * 130 + i + 1) * 130 + (j + 1)) * 32;
#pragma unroll
  for (int icg = 0; icg < 4; ++icg) {
    const short8 h00 = *(const short8*)(xh + base00 + icg * 8);
    const short8 l00 = *(const short8*)(xl + base00 + icg * 8);
    const short8 h01 = *(const short8*)(xh + base00 + 32 + icg * 8);
    const short8 l01 = *(const short8*)(xl + base00 + 32 + icg * 8);
    const short8 h10 = *(const short8*)(xh + base00 + 130 * 32 + icg * 8);
    const short8 l10 = *(const short8*)(xl + base00 + 130 * 32 + icg * 8);
    const short8 h11 = *(const short8*)(xh + base00 + 130 * 32 + 32 + icg * 8);
    const short8 l11 = *(const short8*)(xl + base00 + 130 * 32 + 32 + icg * 8);
#pragma unroll
    for (int kk = 0; kk < 8; ++kk) {
      const int ic = icg * 8 + kk;
      const float x00 = bf2f(h00[kk], l00[kk]);
      const float x01 = bf2f(h01[kk], l01[kk]);
      const float x10 = bf2f(h10[kk], l10[kk]);
      const float x11 = bf2f(h11[kk], l11[kk]);
      const float* wp = w + ic * 9;
      a00 = fmaf(x00, wp[4], a00);
      a01 = fmaf(x00, wp[5], fmaf(x01, wp[3], a01));
      a10 = fmaf(x00, wp[7], fmaf(x10, wp[1], a10));
      a11 = fmaf(x00, wp[8], fmaf(x01, wp[6], fmaf(x10, wp[2], fmaf(x11, wp[0], a11))));
    }
  }
  float* op = out + ((size_t)nl * 256 + 2 * i) * 256 + 2 * j;
  op[0] = a00; op[1] = a01; op[256] = a10; op[257] = a11;
}

// ---------------------------------------------------------------------------
extern "C" void kernel_launch(void* const* d_in, const int* in_sizes, int n_in,
                              void* d_out, int out_size, void* d_ws, size_t ws_size,
                              hipStream_t stream) {
  const float* x   = (const float*)d_in[0];
  const float* w1  = (const float*)d_in[1];
  const float* b1  = (const float*)d_in[2];
  const float* w2  = (const float*)d_in[3];
  const float* b2  = (const float*)d_in[4];
  const float* w3  = (const float*)d_in[5];
  const float* b3  = (const float*)d_in[6];
  const float* w4  = (const float*)d_in[7];
  const float* b4  = (const float*)d_in[8];
  const float* emb = (const float*)d_in[9];
  const float* dw1 = (const float*)d_in[10];
  const float* db1 = (const float*)d_in[11];
  const float* dw2 = (const float*)d_in[12];
  const float* db2 = (const float*)d_in[13];
  const float* dw3 = (const float*)d_in[14];
  const float* db3 = (const float*)d_in[15];
  float* outp = (float*)d_out;

  const int N = in_sizes[0] / (2 * 256 * 256);  // 64
  if (N & 1) return;
  const int NH = N / 2;

  // ---- arena (units: floats; 1 float = 2 shorts) ----
  const size_t sx3 = (size_t)N * 66 * 66 * 64;    // x3in shorts/split; floats for both
  const size_t sx2 = (size_t)NH * 130 * 130 * 32; // x2in shorts/split (half batch)
  const size_t sx4 = (size_t)N * 34 * 34 * 128;
  const size_t se  = (size_t)N * 128 * 1024;
  const size_t sd1 = sx4;
  const size_t smalls = 512 + 18432 + 73728 + 147456 + 73728 + 18432 + 32768;
  const size_t need = (sx3 + sx4 + se + sd1 + smalls) * sizeof(float);
  if (ws_size < need) return;

  float* ws = (float*)d_ws;
  short* x3h = (short*)ws;                 short* x3l = x3h + sx3;   // [A..B]
  short* x2h = (short*)(ws + sx3);         short* x2l = x2h + sx2;   // [A]
  short* x4h = (short*)(ws + sx3);         short* x4l = x4h + sx4;   // [B..C]
  short* ech = (short*)(ws + sx3 + sx4);   short* ecl = ech + se;    // [C..D]
  short* d1h = (short*)(ws + sx3 + sx4 + se); short* d1l = d1h + sd1;// [D..E]
  short* d2h = (short*)ws;                 short* d2l = d2h + sx3;   // [E..F]
  short* d3h = (short*)(ws + sx3);         short* d3l = d3h + sx2;   // [F]
  float* sm  = ws + sx3 + sx4 + se + sd1;
  float* nrm = sm;
  short* a2h = (short*)(sm + 512);                         short* a2l = a2h + 18432;
  short* a3h = (short*)(sm + 512 + 18432);                 short* a3l = a3h + 73728;
  short* a4h = (short*)(sm + 512 + 18432 + 73728);         short* a4l = a4h + 147456;
  short* ad1h = (short*)(sm + 512 + 18432 + 73728 + 147456); short* ad1l = ad1h + 73728;
  short* ad2h = (short*)(sm + 512 + 18432 + 73728 + 147456 + 73728); short* ad2l = ad2h + 18432;
  short* ebh = (short*)(sm + 512 + 18432 + 73728 + 147456 + 73728 + 18432); short* ebl = ebh + 32768;

  // ---- weight preps + VQ tables (smalls region, no conflicts) ----
  wprep_conv<32, 64><<<72, 256, 0, stream>>>(w2, a2h, a2l);
  wprep_conv<64, 128><<<288, 256, 0, stream>>>(w3, a3h, a3l);
  wprep_conv<128, 128><<<576, 256, 0, stream>>>(w4, a4h, a4l);
  wprep_dec<128, 64><<<288, 256, 0, stream>>>(dw1, ad1h, ad1l);
  wprep_dec<64, 32><<<72, 256, 0, stream>>>(dw2, ad2h, ad2l);
  vq_norms<<<2, 256, 0, stream>>>(emb, nrm);
  emb_prep<<<128, 256, 0, stream>>>(emb, ebh, ebl);

  // ---- encoder ----
  ring_zero<<<(int)((NH * 516 * 32 + 255) / 256), 256, 0, stream>>>(x2h, x2l, NH, 130, 130, 32);
  ring_zero<<<(int)(((size_t)N * 260 * 64 + 255) / 256), 256, 0, stream>>>(x3h, x3l, N, 66, 66, 64);
  for (int half = 0; half < 2; ++half) {
    const int n0 = half * NH;
    conv1_xt<<<NH * 16384 / 256, 256, 0, stream>>>(
        x + (size_t)n0 * 2 * 65536, w1, b1, x2h, x2l, NH);
    conv_mfma_xt<32, 64, 64, 64, 2, 130, 130, 66, 66>
        <<<NH * 64, 256, 0, stream>>>(x2h, x2l, a2h, a2l, b2,
                                      x3h + (size_t)n0 * 66 * 66 * 64,
                                      x3l + (size_t)n0 * 66 * 66 * 64);
  }
  ring_zero<<<(int)(((size_t)N * 132 * 128 + 255) / 256), 256, 0, stream>>>(x4h, x4l, N, 34, 34, 128);
  conv_mfma_xt<64, 128, 32, 32, 2, 66, 66, 34, 34>
      <<<N * 16, 256, 0, stream>>>(x3h, x3l, a3h, a3l, b3, x4h, x4l);
  conv4_mfma<<<N * 16, 256, 0, stream>>>(x4h, x4l, a4h, a4l, b4, ech, ecl);

  // ---- VQ ----
  ring_zero<<<(int)(((size_t)N * 132 * 128 + 255) / 256), 256, 0, stream>>>(d1h, d1l, N, 34, 34, 128);
  vq_mfma<<<N * 2048 / 64, 256, 0, stream>>>(ech, ecl, ebh, ebl, nrm, emb, d1h, d1l);

  // ---- decoder ----
  ring_zero<<<(int)(((size_t)N * 260 * 64 + 255) / 256), 256, 0, stream>>>(d2h, d2l, N, 66, 66, 64);
  deconv_mfma_xt<128, 64, 32, 32, 34, 34, 66, 66>
      <<<4 * N * 16, 256, 0, stream>>>(d1h, d1l, ad1h, ad1l, db1, d2h, d2l);
  ring_zero<<<(int)((NH * 516 * 32 + 255) / 256), 256, 0, stream>>>(d3h, d3l, NH, 130, 130, 32);
  for (int half = 0; half < 2; ++half) {
    const int n0 = half * NH;
    deconv_mfma_xt<64, 32, 64, 64, 66, 66, 130, 130>
        <<<4 * NH * 64, 256, 0, stream>>>(d2h + (size_t)n0 * 66 * 66 * 64,
                                          d2l + (size_t)n0 * 66 * 66 * 64,
                                          ad2h, ad2l, db2, d3h, d3l);
    dec3_xt<<<NH * 16384 / 256, 256, 0, stream>>>(
        d3h, d3l, dw3, db3, outp + (size_t)n0 * 65536, NH);
  }
}

// Round 7
// 893.970 us; speedup vs baseline: 3.2253x; 1.1054x over previous
//
#include <hip/hip_runtime.h>

// ---------------------------------------------------------------------------
// VQ-VAE forward (NCHW). Round 7: fused-phase transposed conv.
//  R6 post-mortem: 4-phase deconv blocks were latency-bound (MfmaUtil 7.6%,
//  VALU 8.8%, HBM 18%) — too few MFMAs/block, input re-read 9x across phases.
//  Fix: one block computes ALL 4 phases; the 9 tap-entries share the 2x2
//  input neighborhood, loaded once per icb (8 independent 16B loads).
//  A-frag layout (e,icb,mt) unchanged -> wprep_dec identical. Numerics
//  identical (same split-bf16, same per-acc op order).
//  Everything else unchanged from R6.
// ---------------------------------------------------------------------------

using short8  = __attribute__((ext_vector_type(8))) short;
using short4v = __attribute__((ext_vector_type(4))) short;
using floatx4 = __attribute__((ext_vector_type(4))) float;

__device__ inline unsigned short bf16rn(float f) {
  unsigned u = __float_as_uint(f);
  unsigned r = (u + 0x7fffu + ((u >> 16) & 1u)) >> 16;
  return (unsigned short)r;
}
__device__ inline float bf2f(short h, short l) {
  return __uint_as_float(((unsigned)(unsigned short)h) << 16) +
         __uint_as_float(((unsigned)(unsigned short)l) << 16);
}

// ---- deconv tap tables: entry e -> (ky,kx) weight tap, (di,dj) input pos
// phase order ph0=(0,0) ph1=(0,1) ph2=(1,0) ph3=(1,1)
__device__ const int DKY[9]  = {1, 1, 1, 2, 0, 2, 2, 0, 0};
__device__ const int DKX[9]  = {1, 2, 0, 1, 1, 2, 0, 2, 0};
__device__ const int DDI[9]  = {0, 0, 0, 0, 1, 0, 0, 1, 1};
__device__ const int DDJ[9]  = {0, 0, 1, 0, 0, 0, 1, 0, 1};

// ---------------- ring zero: clear pad ring of xt buffer ------------------
__global__ __launch_bounds__(256) void ring_zero(short* __restrict__ h,
                                                 short* __restrict__ l,
                                                 int nimg, int PH, int PW, int C) {
  const int RC = (2 * PW + 2 * (PH - 2)) * C;
  int t = blockIdx.x * 256 + threadIdx.x;
  if (t >= nimg * RC) return;
  const int nl = t / RC;
  int rem = t - nl * RC;
  const int p = rem / C;
  const int ch = rem - p * C;
  int r, c;
  if (p < 2 * PW) {
    r = (p < PW) ? 0 : PH - 1;
    c = (p < PW) ? p : p - PW;
  } else {
    int q = p - 2 * PW;
    if (q < PH - 2) { r = 1 + q; c = 0; }
    else { r = 1 + q - (PH - 2); c = PW - 1; }
  }
  const size_t a = (((size_t)nl * PH + r) * PW + c) * C + ch;
  h[a] = 0; l[a] = 0;
}

// ---------------- conv1: fp32 direct, writes xt [nh][130][130][32] --------
__global__ __launch_bounds__(256) void conv1_xt(const float* __restrict__ x,
                                                const float* __restrict__ w,
                                                const float* __restrict__ bias,
                                                short* __restrict__ oh,
                                                short* __restrict__ ol, int NH) {
  int t = blockIdx.x * 256 + threadIdx.x;
  if (t >= NH * 128 * 128) return;
  const int px = t & 16383;
  const int n  = t >> 14;
  const int r = px >> 7, c = px & 127;
  const int ih0 = 2 * r - 1, iw0 = 2 * c - 1;
  float acc[32];
#pragma unroll
  for (int o = 0; o < 32; ++o) acc[o] = bias[o];
  const float* ip = x + (size_t)n * 2 * 65536;
#pragma unroll
  for (int ic = 0; ic < 2; ++ic, ip += 65536) {
    float v[9];
#pragma unroll
    for (int kh = 0; kh < 3; ++kh) {
      const int ih = ih0 + kh;
#pragma unroll
      for (int kw = 0; kw < 3; ++kw) {
        const int iw = iw0 + kw;
        const bool ok = (ih >= 0) && (ih < 256) && (iw >= 0) && (iw < 256);
        v[kh * 3 + kw] = ok ? ip[ih * 256 + iw] : 0.f;
      }
    }
#pragma unroll
    for (int o = 0; o < 32; ++o) {
      float s = acc[o];
#pragma unroll
      for (int k = 0; k < 9; ++k) s = fmaf(v[k], w[(o * 2 + ic) * 9 + k], s);
      acc[o] = s;
    }
  }
  const size_t base = (((size_t)n * 130 + r + 1) * 130 + (c + 1)) * 32;
  short8 vh[4], vl[4];
#pragma unroll
  for (int g = 0; g < 4; ++g) {
#pragma unroll
    for (int kk = 0; kk < 8; ++kk) {
      const float rv = fmaxf(acc[g * 8 + kk], 0.f);
      const unsigned short hh = bf16rn(rv);
      vh[g][kk] = (short)hh;
      vl[g][kk] = (short)bf16rn(rv - __uint_as_float((unsigned)hh << 16));
    }
    *(short8*)(oh + base + g * 8) = vh[g];
    *(short8*)(ol + base + g * 8) = vl[g];
  }
}

// ---------------- generic A-frag prep: conv weights [COUT][CIN][3][3] -----
template<int CIN, int COUT>
__global__ __launch_bounds__(256) void wprep_conv(const float* __restrict__ w,
                                                  short* __restrict__ hi,
                                                  short* __restrict__ lo) {
  constexpr int MT = COUT / 16;
  const int t = blockIdx.x * 256 + threadIdx.x;
  const int j = t & 7;
  const int lane = (t >> 3) & 63;
  const int g = t >> 9;
  const int mt = g % MT;
  const int s = g / MT;
  const int icb = s / 9, tap = s - icb * 9;
  const int kh = tap / 3, kw = tap - kh * 3;
  const int m = mt * 16 + (lane & 15);
  const int ic = icb * 32 + ((lane >> 4) << 3) + j;
  const float v = w[((m * CIN + ic) * 3 + kh) * 3 + kw];
  const unsigned short h = bf16rn(v);
  hi[t] = (short)h;
  lo[t] = (short)bf16rn(v - __uint_as_float((unsigned)h << 16));
}

// ---------------- deconv A-frag prep: weights [CIN][COUT][3][3] -----------
template<int CIN, int COUT>
__global__ __launch_bounds__(256) void wprep_dec(const float* __restrict__ w,
                                                 short* __restrict__ hi,
                                                 short* __restrict__ lo) {
  constexpr int MT = COUT / 16, ICB = CIN / 32;
  const int t = blockIdx.x * 256 + threadIdx.x;
  const int j = t & 7;
  const int lane = (t >> 3) & 63;
  const int g = t >> 9;
  const int mt = g % MT;
  const int u = g / MT;
  const int icb = u % ICB;
  const int e = u / ICB;
  const int ky = DKY[e], kx = DKX[e];
  const int m = mt * 16 + (lane & 15);
  const int ic = icb * 32 + ((lane >> 4) << 3) + j;
  const float v = w[((ic * COUT + m) * 3 + ky) * 3 + kx];
  const unsigned short h = bf16rn(v);
  hi[t] = (short)h;
  lo[t] = (short)bf16rn(v - __uint_as_float((unsigned)h << 16));
}

// ---------------- generic strided conv MFMA (xt in -> xt out, relu) -------
template<int CIN, int COUT, int OH, int OW, int S, int PHI, int PWI, int PHO, int PWO>
__global__ __launch_bounds__(256) void conv_mfma_xt(
    const short* __restrict__ xih, const short* __restrict__ xil,
    const short* __restrict__ ah,  const short* __restrict__ al,
    const float* __restrict__ bias,
    short* __restrict__ xoh, short* __restrict__ xol) {
  constexpr int MT = COUT / 16, ICB = CIN / 32, TPB = OH * OW / 64;
  const int b = blockIdx.x;
  const int n = b / TPB, pt = b % TPB;
  const int lane = threadIdx.x & 63, wave = threadIdx.x >> 6;
  const int pl = pt * 64 + wave * 16 + (lane & 15);
  const int r = pl / OW, c = pl % OW;
  const int quad = lane >> 4;

  floatx4 acc[MT];
#pragma unroll
  for (int mt = 0; mt < MT; ++mt) acc[mt] = (floatx4){0.f, 0.f, 0.f, 0.f};

  const size_t bbase = (((size_t)n * PHI + S * r) * PWI + S * c) * CIN + quad * 8;
  const short8* __restrict__ ah8 = (const short8*)ah;
  const short8* __restrict__ al8 = (const short8*)al;

  for (int icb = 0; icb < ICB; ++icb) {
#pragma unroll
    for (int tap = 0; tap < 9; ++tap) {
      const int kh = tap / 3, kw = tap - kh * 3;
      const size_t be = bbase + (size_t)(kh * PWI + kw) * CIN + icb * 32;
      const short8 bh = *(const short8*)(xih + be);
      const short8 bl = *(const short8*)(xil + be);
#pragma unroll
      for (int mt = 0; mt < MT; ++mt) {
        const int fi = ((icb * 9 + tap) * MT + mt) * 64 + lane;
        const short8 wh = ah8[fi];
        const short8 wl = al8[fi];
        acc[mt] = __builtin_amdgcn_mfma_f32_16x16x32_bf16(wh, bh, acc[mt], 0, 0, 0);
        acc[mt] = __builtin_amdgcn_mfma_f32_16x16x32_bf16(wh, bl, acc[mt], 0, 0, 0);
        acc[mt] = __builtin_amdgcn_mfma_f32_16x16x32_bf16(wl, bh, acc[mt], 0, 0, 0);
      }
    }
  }
  const size_t ob = (((size_t)n * PHO + r + 1) * PWO + (c + 1)) * COUT + quad * 4;
#pragma unroll
  for (int mt = 0; mt < MT; ++mt) {
    short4v sh, sl;
#pragma unroll
    for (int q = 0; q < 4; ++q) {
      const float v = fmaxf(acc[mt][q] + bias[mt * 16 + quad * 4 + q], 0.f);
      const unsigned short hh = bf16rn(v);
      sh[q] = (short)hh;
      sl[q] = (short)bf16rn(v - __uint_as_float((unsigned)hh << 16));
    }
    *(short4v*)(xoh + ob + mt * 16) = sh;
    *(short4v*)(xol + ob + mt * 16) = sl;
  }
}

// ---------- fused transposed conv MFMA: all 4 phases in one block ---------
// Entry e -> phase PHE[e], input pos DE[e] (di*2+dj). 2x2 input neighborhood
// loaded once per icb; 9 tap-groups; A-frag layout (e,icb,mt) as wprep_dec.
template<int CIN, int COUT, int IH, int IW, int PHI, int PWI, int PHO, int PWO>
__global__ __launch_bounds__(256) void deconv_fused_xt(
    const short* __restrict__ xih, const short* __restrict__ xil,
    const short* __restrict__ ah,  const short* __restrict__ al,
    const float* __restrict__ bias,
    short* __restrict__ xoh, short* __restrict__ xol) {
  constexpr int MT = COUT / 16, ICB = CIN / 32, TPB = IH * IW / 64;
  constexpr int PHE[9] = {0, 1, 1, 2, 2, 3, 3, 3, 3};
  constexpr int DE[9]  = {0, 0, 1, 0, 2, 0, 1, 2, 3};
  const int b = blockIdx.x;
  const int n = b / TPB, pt = b % TPB;
  const int lane = threadIdx.x & 63, wave = threadIdx.x >> 6;
  const int pl = pt * 64 + wave * 16 + (lane & 15);
  const int i = pl / IW, j = pl % IW;
  const int quad = lane >> 4;

  floatx4 acc[4][MT];
#pragma unroll
  for (int ph = 0; ph < 4; ++ph)
#pragma unroll
    for (int mt = 0; mt < MT; ++mt) acc[ph][mt] = (floatx4){0.f, 0.f, 0.f, 0.f};

  const short8* __restrict__ ah8 = (const short8*)ah;
  const short8* __restrict__ al8 = (const short8*)al;
  const size_t p00 = (((size_t)n * PHI + (i + 1)) * PWI + (j + 1)) * CIN + quad * 8;

  for (int icb = 0; icb < ICB; ++icb) {
    short8 bh[4], bl[4];
#pragma unroll
    for (int d = 0; d < 4; ++d) {
      const size_t be = p00 + (size_t)((d >> 1) * PWI + (d & 1)) * CIN + icb * 32;
      bh[d] = *(const short8*)(xih + be);
      bl[d] = *(const short8*)(xil + be);
    }
#pragma unroll
    for (int e = 0; e < 9; ++e) {
      const int ph = PHE[e], d = DE[e];
#pragma unroll
      for (int mt = 0; mt < MT; ++mt) {
        const int fi = ((e * ICB + icb) * MT + mt) * 64 + lane;
        const short8 wh = ah8[fi];
        const short8 wl = al8[fi];
        acc[ph][mt] = __builtin_amdgcn_mfma_f32_16x16x32_bf16(wh, bh[d], acc[ph][mt], 0, 0, 0);
        acc[ph][mt] = __builtin_amdgcn_mfma_f32_16x16x32_bf16(wh, bl[d], acc[ph][mt], 0, 0, 0);
        acc[ph][mt] = __builtin_amdgcn_mfma_f32_16x16x32_bf16(wl, bh[d], acc[ph][mt], 0, 0, 0);
      }
    }
  }
#pragma unroll
  for (int ph = 0; ph < 4; ++ph) {
    const int oy = 2 * i + (ph >> 1), ox = 2 * j + (ph & 1);
    const size_t ob = (((size_t)n * PHO + oy + 1) * PWO + (ox + 1)) * COUT + quad * 4;
#pragma unroll
    for (int mt = 0; mt < MT; ++mt) {
      short4v sh, sl;
#pragma unroll
      for (int q = 0; q < 4; ++q) {
        const float v = fmaxf(acc[ph][mt][q] + bias[mt * 16 + quad * 4 + q], 0.f);
        const unsigned short hh = bf16rn(v);
        sh[q] = (short)hh;
        sl[q] = (short)bf16rn(v - __uint_as_float((unsigned)hh << 16));
      }
      *(short4v*)(xoh + ob + mt * 16) = sh;
      *(short4v*)(xol + ob + mt * 16) = sl;
    }
  }
}

// ---------------- conv4 MFMA (R4/R5 proven, unchanged) --------------------
__global__ __launch_bounds__(256) void conv4_mfma(
    const short* __restrict__ xthi, const short* __restrict__ xtlo,
    const short* __restrict__ ahi,  const short* __restrict__ alo,
    const float* __restrict__ bias,
    short* __restrict__ ench, short* __restrict__ encl) {
  const int b    = blockIdx.x;
  const int n    = b >> 4;
  const int pt   = b & 15;
  const int lane = threadIdx.x & 63;
  const int wave = threadIdx.x >> 6;
  const int pl   = wave * 16 + (lane & 15);
  const int r    = 2 * pt + (pl >> 5);
  const int c    = pl & 31;
  const int kq   = lane >> 4;

  floatx4 acc[8];
#pragma unroll
  for (int mt = 0; mt < 8; ++mt) acc[mt] = (floatx4){0.f, 0.f, 0.f, 0.f};

  const size_t bbase = (((size_t)n * 34 + r) * 34 + c) * 128 + kq * 8;
  const short8* __restrict__ ah8 = (const short8*)ahi;
  const short8* __restrict__ al8 = (const short8*)alo;

  int s = 0;
  for (int icb = 0; icb < 4; ++icb) {
#pragma unroll
    for (int tap = 0; tap < 9; ++tap, ++s) {
      const int kh = tap / 3, kw = tap - kh * 3;
      const size_t be = bbase + (size_t)(kh * 34 + kw) * 128 + icb * 32;
      const short8 bh = *(const short8*)(xthi + be);
      const short8 bl = *(const short8*)(xtlo + be);
#pragma unroll
      for (int mt = 0; mt < 8; ++mt) {
        const int fi = ((s * 8 + mt) << 6) + lane;
        const short8 ah = ah8[fi];
        const short8 al = al8[fi];
        acc[mt] = __builtin_amdgcn_mfma_f32_16x16x32_bf16(ah, bh, acc[mt], 0, 0, 0);
        acc[mt] = __builtin_amdgcn_mfma_f32_16x16x32_bf16(ah, bl, acc[mt], 0, 0, 0);
        acc[mt] = __builtin_amdgcn_mfma_f32_16x16x32_bf16(al, bh, acc[mt], 0, 0, 0);
      }
    }
  }
  const size_t obase = (size_t)n * 128 * 1024 + (pt * 64 + pl);
#pragma unroll
  for (int mt = 0; mt < 8; ++mt) {
#pragma unroll
    for (int q = 0; q < 4; ++q) {
      const int cout = mt * 16 + kq * 4 + q;
      const float rr = fmaxf(acc[mt][q] + bias[cout], 0.f);
      const unsigned short h = bf16rn(rr);
      const size_t oi = obase + (size_t)cout * 1024;
      ench[oi] = (short)h;
      encl[oi] = (short)bf16rn(rr - __uint_as_float((unsigned)h << 16));
    }
  }
}

// ------------------------------- VQ ---------------------------------------
__global__ __launch_bounds__(256) void vq_norms(const float* __restrict__ emb,
                                                float* __restrict__ norms) {
  int jj = blockIdx.x * 256 + threadIdx.x;
  if (jj < 512) {
    float s = 0.f;
    const float* e = emb + jj * 64;
#pragma unroll
    for (int k = 0; k < 64; ++k) s = fmaf(e[k], e[k], s);
    norms[jj] = s;
  }
}

__global__ __launch_bounds__(256) void emb_prep(const float* __restrict__ emb,
                                                short* __restrict__ hi,
                                                short* __restrict__ lo) {
  const int t = blockIdx.x * 256 + threadIdx.x;  // < 32768
  const int j  = t & 7;
  const int l  = (t >> 3) & 63;
  const int kk = (t >> 9) & 1;
  const int ct = t >> 10;
  const int code = ct * 16 + (l & 15);
  const int k = kk * 32 + ((l >> 4) << 3) + j;
  const float v = emb[code * 64 + k];
  const unsigned short h = bf16rn(v);
  hi[t] = (short)h;
  lo[t] = (short)bf16rn(v - __uint_as_float((unsigned)h << 16));
}

__global__ __launch_bounds__(256) void vq_mfma(
    const short* __restrict__ fhi, const short* __restrict__ flo,
    const short* __restrict__ ebh, const short* __restrict__ ebl,
    const float* __restrict__ nrm, const float* __restrict__ emb,
    short* __restrict__ d1h, short* __restrict__ d1l) {
  __shared__ int sidx[64];
  const int lane = threadIdx.x & 63;
  const int wave = threadIdx.x >> 6;
  const int r0 = blockIdx.x * 64 + wave * 16;
  const size_t abase = ((size_t)(r0 + (lane & 15))) * 64 + ((lane >> 4) << 3);
  short8 ah0 = *(const short8*)(fhi + abase);
  short8 ah1 = *(const short8*)(fhi + abase + 32);
  short8 al0 = *(const short8*)(flo + abase);
  short8 al1 = *(const short8*)(flo + abase + 32);

  float bestv[4] = {3.4e38f, 3.4e38f, 3.4e38f, 3.4e38f};
  int   besti[4] = {0, 0, 0, 0};
  const short8* __restrict__ ebh8 = (const short8*)ebh;
  const short8* __restrict__ ebl8 = (const short8*)ebl;
  for (int ct = 0; ct < 32; ++ct) {
    const int f0 = (ct * 2) * 64 + lane;
    const short8 b0h = ebh8[f0];
    const short8 b1h = ebh8[f0 + 64];
    const short8 b0l = ebl8[f0];
    const short8 b1l = ebl8[f0 + 64];
    floatx4 acc = {0.f, 0.f, 0.f, 0.f};
    acc = __builtin_amdgcn_mfma_f32_16x16x32_bf16(ah0, b0h, acc, 0, 0, 0);
    acc = __builtin_amdgcn_mfma_f32_16x16x32_bf16(ah1, b1h, acc, 0, 0, 0);
    acc = __builtin_amdgcn_mfma_f32_16x16x32_bf16(ah0, b0l, acc, 0, 0, 0);
    acc = __builtin_amdgcn_mfma_f32_16x16x32_bf16(ah1, b1l, acc, 0, 0, 0);
    acc = __builtin_amdgcn_mfma_f32_16x16x32_bf16(al0, b0h, acc, 0, 0, 0);
    acc = __builtin_amdgcn_mfma_f32_16x16x32_bf16(al1, b1h, acc, 0, 0, 0);
    const int code = ct * 16 + (lane & 15);
    const float nn = nrm[code];
#pragma unroll
    for (int q = 0; q < 4; ++q) {
      const float sc = nn - 2.f * acc[q];
      if (sc < bestv[q]) { bestv[q] = sc; besti[q] = code; }
    }
  }
#pragma unroll
  for (int off = 1; off < 16; off <<= 1) {
#pragma unroll
    for (int q = 0; q < 4; ++q) {
      const float ov = __shfl_xor(bestv[q], off, 64);
      const int   oi = __shfl_xor(besti[q], off, 64);
      if (ov < bestv[q] || (ov == bestv[q] && oi < besti[q])) {
        bestv[q] = ov; besti[q] = oi;
      }
    }
  }
  if ((lane & 15) == 0) {
#pragma unroll
    for (int q = 0; q < 4; ++q)
      sidx[wave * 16 + (lane >> 4) * 4 + q] = besti[q];
  }
  __syncthreads();
  const int row  = threadIdx.x >> 2;
  const int part = threadIdx.x & 3;
  const int rid = blockIdx.x * 64 + row;
  const int n  = rid >> 11;
  const int ch = (rid >> 4) & 127;
  const int pb = rid & 15;
  const int gi = sidx[row];
  const float4* src = (const float4*)(emb + (size_t)gi * 64 + part * 16);
  float4 v0 = src[0], v1 = src[1], v2 = src[2], v3 = src[3];
  float vals[16] = {v0.x, v0.y, v0.z, v0.w, v1.x, v1.y, v1.z, v1.w,
                    v2.x, v2.y, v2.z, v2.w, v3.x, v3.y, v3.z, v3.w};
#pragma unroll
  for (int kk = 0; kk < 16; ++kk) {
    const int k = part * 16 + kk;
    const int pix = pb * 64 + k;
    const int r = pix >> 5, c = pix & 31;
    const size_t a = (((size_t)n * 34 + r + 1) * 34 + (c + 1)) * 128 + ch;
    const unsigned short h = bf16rn(vals[kk]);
    d1h[a] = (short)h;
    d1l[a] = (short)bf16rn(vals[kk] - __uint_as_float((unsigned)h << 16));
  }
}

// ---------------- dec3: fp32 direct from split-bf16 xt input --------------
__global__ __launch_bounds__(256) void dec3_xt(const short* __restrict__ xh,
                                               const short* __restrict__ xl,
                                               const float* __restrict__ w,
                                               const float* __restrict__ bias,
                                               float* __restrict__ out, int NH) {
  int t = blockIdx.x * 256 + threadIdx.x;
  if (t >= NH * 128 * 128) return;
  const int px = t & 16383;
  const int nl = t >> 14;
  const int i = px >> 7, j = px & 127;
  const float b0 = bias[0];
  float a00 = b0, a01 = b0, a10 = b0, a11 = b0;
  const size_t base00 = (((size_t)nl * 130 + i + 1) * 130 + (j + 1)) * 32;
#pragma unroll
  for (int icg = 0; icg < 4; ++icg) {
    const short8 h00 = *(const short8*)(xh + base00 + icg * 8);
    const short8 l00 = *(const short8*)(xl + base00 + icg * 8);
    const short8 h01 = *(const short8*)(xh + base00 + 32 + icg * 8);
    const short8 l01 = *(const short8*)(xl + base00 + 32 + icg * 8);
    const short8 h10 = *(const short8*)(xh + base00 + 130 * 32 + icg * 8);
    const short8 l10 = *(const short8*)(xl + base00 + 130 * 32 + icg * 8);
    const short8 h11 = *(const short8*)(xh + base00 + 130 * 32 + 32 + icg * 8);
    const short8 l11 = *(const short8*)(xl + base00 + 130 * 32 + 32 + icg * 8);
#pragma unroll
    for (int kk = 0; kk < 8; ++kk) {
      const int ic = icg * 8 + kk;
      const float x00 = bf2f(h00[kk], l00[kk]);
      const float x01 = bf2f(h01[kk], l01[kk]);
      const float x10 = bf2f(h10[kk], l10[kk]);
      const float x11 = bf2f(h11[kk], l11[kk]);
      const float* wp = w + ic * 9;
      a00 = fmaf(x00, wp[4], a00);
      a01 = fmaf(x00, wp[5], fmaf(x01, wp[3], a01));
      a10 = fmaf(x00, wp[7], fmaf(x10, wp[1], a10));
      a11 = fmaf(x00, wp[8], fmaf(x01, wp[6], fmaf(x10, wp[2], fmaf(x11, wp[0], a11))));
    }
  }
  float* op = out + ((size_t)nl * 256 + 2 * i) * 256 + 2 * j;
  op[0] = a00; op[1] = a01; op[256] = a10; op[257] = a11;
}

// ---------------------------------------------------------------------------
extern "C" void kernel_launch(void* const* d_in, const int* in_sizes, int n_in,
                              void* d_out, int out_size, void* d_ws, size_t ws_size,
                              hipStream_t stream) {
  const float* x   = (const float*)d_in[0];
  const float* w1  = (const float*)d_in[1];
  const float* b1  = (const float*)d_in[2];
  const float* w2  = (const float*)d_in[3];
  const float* b2  = (const float*)d_in[4];
  const float* w3  = (const float*)d_in[5];
  const float* b3  = (const float*)d_in[6];
  const float* w4  = (const float*)d_in[7];
  const float* b4  = (const float*)d_in[8];
  const float* emb = (const float*)d_in[9];
  const float* dw1 = (const float*)d_in[10];
  const float* db1 = (const float*)d_in[11];
  const float* dw2 = (const float*)d_in[12];
  const float* db2 = (const float*)d_in[13];
  const float* dw3 = (const float*)d_in[14];
  const float* db3 = (const float*)d_in[15];
  float* outp = (float*)d_out;

  const int N = in_sizes[0] / (2 * 256 * 256);  // 64
  if (N & 1) return;
  const int NH = N / 2;

  // ---- arena (units: floats; 1 float = 2 shorts) ----
  const size_t sx3 = (size_t)N * 66 * 66 * 64;
  const size_t sx2 = (size_t)NH * 130 * 130 * 32;
  const size_t sx4 = (size_t)N * 34 * 34 * 128;
  const size_t se  = (size_t)N * 128 * 1024;
  const size_t sd1 = sx4;
  const size_t smalls = 512 + 18432 + 73728 + 147456 + 73728 + 18432 + 32768;
  const size_t need = (sx3 + sx4 + se + sd1 + smalls) * sizeof(float);
  if (ws_size < need) return;

  float* ws = (float*)d_ws;
  short* x3h = (short*)ws;                 short* x3l = x3h + sx3;
  short* x2h = (short*)(ws + sx3);         short* x2l = x2h + sx2;
  short* x4h = (short*)(ws + sx3);         short* x4l = x4h + sx4;
  short* ech = (short*)(ws + sx3 + sx4);   short* ecl = ech + se;
  short* d1h = (short*)(ws + sx3 + sx4 + se); short* d1l = d1h + sd1;
  short* d2h = (short*)ws;                 short* d2l = d2h + sx3;
  short* d3h = (short*)(ws + sx3);         short* d3l = d3h + sx2;
  float* sm  = ws + sx3 + sx4 + se + sd1;
  float* nrm = sm;
  short* a2h = (short*)(sm + 512);                         short* a2l = a2h + 18432;
  short* a3h = (short*)(sm + 512 + 18432);                 short* a3l = a3h + 73728;
  short* a4h = (short*)(sm + 512 + 18432 + 73728);         short* a4l = a4h + 147456;
  short* ad1h = (short*)(sm + 512 + 18432 + 73728 + 147456); short* ad1l = ad1h + 73728;
  short* ad2h = (short*)(sm + 512 + 18432 + 73728 + 147456 + 73728); short* ad2l = ad2h + 18432;
  short* ebh = (short*)(sm + 512 + 18432 + 73728 + 147456 + 73728 + 18432); short* ebl = ebh + 32768;

  // ---- weight preps + VQ tables ----
  wprep_conv<32, 64><<<72, 256, 0, stream>>>(w2, a2h, a2l);
  wprep_conv<64, 128><<<288, 256, 0, stream>>>(w3, a3h, a3l);
  wprep_conv<128, 128><<<576, 256, 0, stream>>>(w4, a4h, a4l);
  wprep_dec<128, 64><<<288, 256, 0, stream>>>(dw1, ad1h, ad1l);
  wprep_dec<64, 32><<<72, 256, 0, stream>>>(dw2, ad2h, ad2l);
  vq_norms<<<2, 256, 0, stream>>>(emb, nrm);
  emb_prep<<<128, 256, 0, stream>>>(emb, ebh, ebl);

  // ---- encoder ----
  ring_zero<<<(int)((NH * 516 * 32 + 255) / 256), 256, 0, stream>>>(x2h, x2l, NH, 130, 130, 32);
  ring_zero<<<(int)(((size_t)N * 260 * 64 + 255) / 256), 256, 0, stream>>>(x3h, x3l, N, 66, 66, 64);
  for (int half = 0; half < 2; ++half) {
    const int n0 = half * NH;
    conv1_xt<<<NH * 16384 / 256, 256, 0, stream>>>(
        x + (size_t)n0 * 2 * 65536, w1, b1, x2h, x2l, NH);
    conv_mfma_xt<32, 64, 64, 64, 2, 130, 130, 66, 66>
        <<<NH * 64, 256, 0, stream>>>(x2h, x2l, a2h, a2l, b2,
                                      x3h + (size_t)n0 * 66 * 66 * 64,
                                      x3l + (size_t)n0 * 66 * 66 * 64);
  }
  ring_zero<<<(int)(((size_t)N * 132 * 128 + 255) / 256), 256, 0, stream>>>(x4h, x4l, N, 34, 34, 128);
  conv_mfma_xt<64, 128, 32, 32, 2, 66, 66, 34, 34>
      <<<N * 16, 256, 0, stream>>>(x3h, x3l, a3h, a3l, b3, x4h, x4l);
  conv4_mfma<<<N * 16, 256, 0, stream>>>(x4h, x4l, a4h, a4l, b4, ech, ecl);

  // ---- VQ ----
  ring_zero<<<(int)(((size_t)N * 132 * 128 + 255) / 256), 256, 0, stream>>>(d1h, d1l, N, 34, 34, 128);
  vq_mfma<<<N * 2048 / 64, 256, 0, stream>>>(ech, ecl, ebh, ebl, nrm, emb, d1h, d1l);

  // ---- decoder (fused-phase deconv) ----
  ring_zero<<<(int)(((size_t)N * 260 * 64 + 255) / 256), 256, 0, stream>>>(d2h, d2l, N, 66, 66, 64);
  deconv_fused_xt<128, 64, 32, 32, 34, 34, 66, 66>
      <<<N * 16, 256, 0, stream>>>(d1h, d1l, ad1h, ad1l, db1, d2h, d2l);
  ring_zero<<<(int)((NH * 516 * 32 + 255) / 256), 256, 0, stream>>>(d3h, d3l, NH, 130, 130, 32);
  for (int half = 0; half < 2; ++half) {
    const int n0 = half * NH;
    deconv_fused_xt<64, 32, 64, 64, 66, 66, 130, 130>
        <<<NH * 64, 256, 0, stream>>>(d2h + (size_t)n0 * 66 * 66 * 64,
                                      d2l + (size_t)n0 * 66 * 66 * 64,
                                      ad2h, ad2l, db2, d3h, d3l);
    dec3_xt<<<NH * 16384 / 256, 256, 0, stream>>>(
        d3h, d3l, dw3, db3, outp + (size_t)n0 * 65536, NH);
  }
}

// Round 8
// 682.324 us; speedup vs baseline: 4.2258x; 1.3102x over previous
//
#include <hip/hip_runtime.h>

// ---------------------------------------------------------------------------
// VQ-VAE forward (NCHW). Round 8: plain-bf16 decoder + NP=2 deconv tiling.
//  R7 post-mortem: fused deconv still latency-bound (MfmaUtil 8.9%) — A-frag
//  loads (72/icb hi+lo) dominate. Decoder precision only needs ~3% rel
//  (threshold = 8*bf16eps*max|ref|), so decoder goes single-bf16:
//  3x fewer MFMAs, 2x fewer loads, 2x less activation traffic. Each wave now
//  processes NP=2 pixel-tiles so every A-frag load feeds 2 independent MFMAs.
//  Encoder + VQ scoring keep split-bf16 (argmin-safe, proven R4-R7).
// ---------------------------------------------------------------------------

using short8  = __attribute__((ext_vector_type(8))) short;
using short4v = __attribute__((ext_vector_type(4))) short;
using floatx4 = __attribute__((ext_vector_type(4))) float;

__device__ inline unsigned short bf16rn(float f) {
  unsigned u = __float_as_uint(f);
  unsigned r = (u + 0x7fffu + ((u >> 16) & 1u)) >> 16;
  return (unsigned short)r;
}
__device__ inline float bf2f1(short h) {
  return __uint_as_float(((unsigned)(unsigned short)h) << 16);
}

// ---- deconv tap tables: entry e -> (ky,kx) weight tap
__device__ const int DKY[9]  = {1, 1, 1, 2, 0, 2, 2, 0, 0};
__device__ const int DKX[9]  = {1, 2, 0, 1, 1, 2, 0, 2, 0};

// ---------------- ring zero (split pair) ----------------------------------
__global__ __launch_bounds__(256) void ring_zero(short* __restrict__ h,
                                                 short* __restrict__ l,
                                                 int nimg, int PH, int PW, int C) {
  const int RC = (2 * PW + 2 * (PH - 2)) * C;
  int t = blockIdx.x * 256 + threadIdx.x;
  if (t >= nimg * RC) return;
  const int nl = t / RC;
  int rem = t - nl * RC;
  const int p = rem / C;
  const int ch = rem - p * C;
  int r, c;
  if (p < 2 * PW) {
    r = (p < PW) ? 0 : PH - 1;
    c = (p < PW) ? p : p - PW;
  } else {
    int q = p - 2 * PW;
    if (q < PH - 2) { r = 1 + q; c = 0; }
    else { r = 1 + q - (PH - 2); c = PW - 1; }
  }
  const size_t a = (((size_t)nl * PH + r) * PW + c) * C + ch;
  h[a] = 0; l[a] = 0;
}

// ---------------- ring zero (single buffer) -------------------------------
__global__ __launch_bounds__(256) void ring_zero1(short* __restrict__ h,
                                                  int nimg, int PH, int PW, int C) {
  const int RC = (2 * PW + 2 * (PH - 2)) * C;
  int t = blockIdx.x * 256 + threadIdx.x;
  if (t >= nimg * RC) return;
  const int nl = t / RC;
  int rem = t - nl * RC;
  const int p = rem / C;
  const int ch = rem - p * C;
  int r, c;
  if (p < 2 * PW) {
    r = (p < PW) ? 0 : PH - 1;
    c = (p < PW) ? p : p - PW;
  } else {
    int q = p - 2 * PW;
    if (q < PH - 2) { r = 1 + q; c = 0; }
    else { r = 1 + q - (PH - 2); c = PW - 1; }
  }
  h[(((size_t)nl * PH + r) * PW + c) * C + ch] = 0;
}

// ---------------- conv1: fp32 direct, writes xt [nh][130][130][32] --------
__global__ __launch_bounds__(256) void conv1_xt(const float* __restrict__ x,
                                                const float* __restrict__ w,
                                                const float* __restrict__ bias,
                                                short* __restrict__ oh,
                                                short* __restrict__ ol, int NH) {
  int t = blockIdx.x * 256 + threadIdx.x;
  if (t >= NH * 128 * 128) return;
  const int px = t & 16383;
  const int n  = t >> 14;
  const int r = px >> 7, c = px & 127;
  const int ih0 = 2 * r - 1, iw0 = 2 * c - 1;
  float acc[32];
#pragma unroll
  for (int o = 0; o < 32; ++o) acc[o] = bias[o];
  const float* ip = x + (size_t)n * 2 * 65536;
#pragma unroll
  for (int ic = 0; ic < 2; ++ic, ip += 65536) {
    float v[9];
#pragma unroll
    for (int kh = 0; kh < 3; ++kh) {
      const int ih = ih0 + kh;
#pragma unroll
      for (int kw = 0; kw < 3; ++kw) {
        const int iw = iw0 + kw;
        const bool ok = (ih >= 0) && (ih < 256) && (iw >= 0) && (iw < 256);
        v[kh * 3 + kw] = ok ? ip[ih * 256 + iw] : 0.f;
      }
    }
#pragma unroll
    for (int o = 0; o < 32; ++o) {
      float s = acc[o];
#pragma unroll
      for (int k = 0; k < 9; ++k) s = fmaf(v[k], w[(o * 2 + ic) * 9 + k], s);
      acc[o] = s;
    }
  }
  const size_t base = (((size_t)n * 130 + r + 1) * 130 + (c + 1)) * 32;
  short8 vh[4], vl[4];
#pragma unroll
  for (int g = 0; g < 4; ++g) {
#pragma unroll
    for (int kk = 0; kk < 8; ++kk) {
      const float rv = fmaxf(acc[g * 8 + kk], 0.f);
      const unsigned short hh = bf16rn(rv);
      vh[g][kk] = (short)hh;
      vl[g][kk] = (short)bf16rn(rv - __uint_as_float((unsigned)hh << 16));
    }
    *(short8*)(oh + base + g * 8) = vh[g];
    *(short8*)(ol + base + g * 8) = vl[g];
  }
}

// ---------------- A-frag prep: conv weights [COUT][CIN][3][3], split ------
template<int CIN, int COUT>
__global__ __launch_bounds__(256) void wprep_conv(const float* __restrict__ w,
                                                  short* __restrict__ hi,
                                                  short* __restrict__ lo) {
  constexpr int MT = COUT / 16;
  const int t = blockIdx.x * 256 + threadIdx.x;
  const int j = t & 7;
  const int lane = (t >> 3) & 63;
  const int g = t >> 9;
  const int mt = g % MT;
  const int s = g / MT;
  const int icb = s / 9, tap = s - icb * 9;
  const int kh = tap / 3, kw = tap - kh * 3;
  const int m = mt * 16 + (lane & 15);
  const int ic = icb * 32 + ((lane >> 4) << 3) + j;
  const float v = w[((m * CIN + ic) * 3 + kh) * 3 + kw];
  const unsigned short h = bf16rn(v);
  hi[t] = (short)h;
  lo[t] = (short)bf16rn(v - __uint_as_float((unsigned)h << 16));
}

// ---------------- deconv A-frag prep: [CIN][COUT][3][3], hi-only ----------
template<int CIN, int COUT>
__global__ __launch_bounds__(256) void wprep_dec_h(const float* __restrict__ w,
                                                   short* __restrict__ hi) {
  constexpr int MT = COUT / 16, ICB = CIN / 32;
  const int t = blockIdx.x * 256 + threadIdx.x;
  const int j = t & 7;
  const int lane = (t >> 3) & 63;
  const int g = t >> 9;
  const int mt = g % MT;
  const int u = g / MT;
  const int icb = u % ICB;
  const int e = u / ICB;
  const int ky = DKY[e], kx = DKX[e];
  const int m = mt * 16 + (lane & 15);
  const int ic = icb * 32 + ((lane >> 4) << 3) + j;
  hi[t] = (short)bf16rn(w[((ic * COUT + m) * 3 + ky) * 3 + kx]);
}

// ---------------- generic strided conv MFMA (split xt -> split xt) --------
template<int CIN, int COUT, int OH, int OW, int S, int PHI, int PWI, int PHO, int PWO>
__global__ __launch_bounds__(256) void conv_mfma_xt(
    const short* __restrict__ xih, const short* __restrict__ xil,
    const short* __restrict__ ah,  const short* __restrict__ al,
    const float* __restrict__ bias,
    short* __restrict__ xoh, short* __restrict__ xol) {
  constexpr int MT = COUT / 16, ICB = CIN / 32, TPB = OH * OW / 64;
  const int b = blockIdx.x;
  const int n = b / TPB, pt = b % TPB;
  const int lane = threadIdx.x & 63, wave = threadIdx.x >> 6;
  const int pl = pt * 64 + wave * 16 + (lane & 15);
  const int r = pl / OW, c = pl % OW;
  const int quad = lane >> 4;

  floatx4 acc[MT];
#pragma unroll
  for (int mt = 0; mt < MT; ++mt) acc[mt] = (floatx4){0.f, 0.f, 0.f, 0.f};

  const size_t bbase = (((size_t)n * PHI + S * r) * PWI + S * c) * CIN + quad * 8;
  const short8* __restrict__ ah8 = (const short8*)ah;
  const short8* __restrict__ al8 = (const short8*)al;

  for (int icb = 0; icb < ICB; ++icb) {
#pragma unroll
    for (int tap = 0; tap < 9; ++tap) {
      const int kh = tap / 3, kw = tap - kh * 3;
      const size_t be = bbase + (size_t)(kh * PWI + kw) * CIN + icb * 32;
      const short8 bh = *(const short8*)(xih + be);
      const short8 bl = *(const short8*)(xil + be);
#pragma unroll
      for (int mt = 0; mt < MT; ++mt) {
        const int fi = ((icb * 9 + tap) * MT + mt) * 64 + lane;
        const short8 wh = ah8[fi];
        const short8 wl = al8[fi];
        acc[mt] = __builtin_amdgcn_mfma_f32_16x16x32_bf16(wh, bh, acc[mt], 0, 0, 0);
        acc[mt] = __builtin_amdgcn_mfma_f32_16x16x32_bf16(wh, bl, acc[mt], 0, 0, 0);
        acc[mt] = __builtin_amdgcn_mfma_f32_16x16x32_bf16(wl, bh, acc[mt], 0, 0, 0);
      }
    }
  }
  const size_t ob = (((size_t)n * PHO + r + 1) * PWO + (c + 1)) * COUT + quad * 4;
#pragma unroll
  for (int mt = 0; mt < MT; ++mt) {
    short4v sh, sl;
#pragma unroll
    for (int q = 0; q < 4; ++q) {
      const float v = fmaxf(acc[mt][q] + bias[mt * 16 + quad * 4 + q], 0.f);
      const unsigned short hh = bf16rn(v);
      sh[q] = (short)hh;
      sl[q] = (short)bf16rn(v - __uint_as_float((unsigned)hh << 16));
    }
    *(short4v*)(xoh + ob + mt * 16) = sh;
    *(short4v*)(xol + ob + mt * 16) = sl;
  }
}

// ---- fused transposed conv, plain bf16, NP pixel-tiles per wave ----------
template<int CIN, int COUT, int IH, int IW, int PHI, int PWI, int PHO, int PWO, int NP>
__global__ __launch_bounds__(256) void deconv_bf16_xt(
    const short* __restrict__ xih, const short* __restrict__ ah,
    const float* __restrict__ bias, short* __restrict__ xoh) {
  constexpr int MT = COUT / 16, ICB = CIN / 32;
  constexpr int PXB = 64 * NP, TPB = IH * IW / PXB;
  constexpr int PHE[9] = {0, 1, 1, 2, 2, 3, 3, 3, 3};
  constexpr int DE[9]  = {0, 0, 1, 0, 2, 0, 1, 2, 3};
  const int b = blockIdx.x;
  const int n = b / TPB, pt = b % TPB;
  const int lane = threadIdx.x & 63, wave = threadIdx.x >> 6;
  const int quad = lane >> 4;
  int ii[NP], jj[NP];
  size_t p00[NP];
#pragma unroll
  for (int p = 0; p < NP; ++p) {
    const int pl = pt * PXB + wave * (16 * NP) + p * 16 + (lane & 15);
    ii[p] = pl / IW; jj[p] = pl % IW;
    p00[p] = (((size_t)n * PHI + (ii[p] + 1)) * PWI + (jj[p] + 1)) * CIN + quad * 8;
  }

  floatx4 acc[4][MT][NP];
#pragma unroll
  for (int ph = 0; ph < 4; ++ph)
#pragma unroll
    for (int mt = 0; mt < MT; ++mt)
#pragma unroll
      for (int p = 0; p < NP; ++p) acc[ph][mt][p] = (floatx4){0.f, 0.f, 0.f, 0.f};

  const short8* __restrict__ ah8 = (const short8*)ah;
  for (int icb = 0; icb < ICB; ++icb) {
    short8 bh[NP][4];
#pragma unroll
    for (int p = 0; p < NP; ++p)
#pragma unroll
      for (int d = 0; d < 4; ++d)
        bh[p][d] = *(const short8*)(xih + p00[p] +
                                    (size_t)((d >> 1) * PWI + (d & 1)) * CIN + icb * 32);
#pragma unroll
    for (int e = 0; e < 9; ++e) {
      const int ph = PHE[e], d = DE[e];
#pragma unroll
      for (int mt = 0; mt < MT; ++mt) {
        const short8 wh = ah8[((e * ICB + icb) * MT + mt) * 64 + lane];
#pragma unroll
        for (int p = 0; p < NP; ++p)
          acc[ph][mt][p] = __builtin_amdgcn_mfma_f32_16x16x32_bf16(
              wh, bh[p][d], acc[ph][mt][p], 0, 0, 0);
      }
    }
  }
#pragma unroll
  for (int p = 0; p < NP; ++p)
#pragma unroll
    for (int ph = 0; ph < 4; ++ph) {
      const int oy = 2 * ii[p] + (ph >> 1), ox = 2 * jj[p] + (ph & 1);
      const size_t ob = (((size_t)n * PHO + oy + 1) * PWO + (ox + 1)) * COUT + quad * 4;
#pragma unroll
      for (int mt = 0; mt < MT; ++mt) {
        short4v sh;
#pragma unroll
        for (int q = 0; q < 4; ++q)
          sh[q] = (short)bf16rn(fmaxf(acc[ph][mt][p][q] + bias[mt * 16 + quad * 4 + q], 0.f));
        *(short4v*)(xoh + ob + mt * 16) = sh;
      }
    }
}

// ---------------- conv4 MFMA (R4-R7 proven, unchanged) --------------------
__global__ __launch_bounds__(256) void conv4_mfma(
    const short* __restrict__ xthi, const short* __restrict__ xtlo,
    const short* __restrict__ ahi,  const short* __restrict__ alo,
    const float* __restrict__ bias,
    short* __restrict__ ench, short* __restrict__ encl) {
  const int b    = blockIdx.x;
  const int n    = b >> 4;
  const int pt   = b & 15;
  const int lane = threadIdx.x & 63;
  const int wave = threadIdx.x >> 6;
  const int pl   = wave * 16 + (lane & 15);
  const int r    = 2 * pt + (pl >> 5);
  const int c    = pl & 31;
  const int kq   = lane >> 4;

  floatx4 acc[8];
#pragma unroll
  for (int mt = 0; mt < 8; ++mt) acc[mt] = (floatx4){0.f, 0.f, 0.f, 0.f};

  const size_t bbase = (((size_t)n * 34 + r) * 34 + c) * 128 + kq * 8;
  const short8* __restrict__ ah8 = (const short8*)ahi;
  const short8* __restrict__ al8 = (const short8*)alo;

  int s = 0;
  for (int icb = 0; icb < 4; ++icb) {
#pragma unroll
    for (int tap = 0; tap < 9; ++tap, ++s) {
      const int kh = tap / 3, kw = tap - kh * 3;
      const size_t be = bbase + (size_t)(kh * 34 + kw) * 128 + icb * 32;
      const short8 bh = *(const short8*)(xthi + be);
      const short8 bl = *(const short8*)(xtlo + be);
#pragma unroll
      for (int mt = 0; mt < 8; ++mt) {
        const int fi = ((s * 8 + mt) << 6) + lane;
        const short8 ah = ah8[fi];
        const short8 al = al8[fi];
        acc[mt] = __builtin_amdgcn_mfma_f32_16x16x32_bf16(ah, bh, acc[mt], 0, 0, 0);
        acc[mt] = __builtin_amdgcn_mfma_f32_16x16x32_bf16(ah, bl, acc[mt], 0, 0, 0);
        acc[mt] = __builtin_amdgcn_mfma_f32_16x16x32_bf16(al, bh, acc[mt], 0, 0, 0);
      }
    }
  }
  const size_t obase = (size_t)n * 128 * 1024 + (pt * 64 + pl);
#pragma unroll
  for (int mt = 0; mt < 8; ++mt) {
#pragma unroll
    for (int q = 0; q < 4; ++q) {
      const int cout = mt * 16 + kq * 4 + q;
      const float rr = fmaxf(acc[mt][q] + bias[cout], 0.f);
      const unsigned short h = bf16rn(rr);
      const size_t oi = obase + (size_t)cout * 1024;
      ench[oi] = (short)h;
      encl[oi] = (short)bf16rn(rr - __uint_as_float((unsigned)h << 16));
    }
  }
}

// ------------------------------- VQ ---------------------------------------
__global__ __launch_bounds__(256) void vq_norms(const float* __restrict__ emb,
                                                float* __restrict__ norms) {
  int jj = blockIdx.x * 256 + threadIdx.x;
  if (jj < 512) {
    float s = 0.f;
    const float* e = emb + jj * 64;
#pragma unroll
    for (int k = 0; k < 64; ++k) s = fmaf(e[k], e[k], s);
    norms[jj] = s;
  }
}

__global__ __launch_bounds__(256) void emb_prep(const float* __restrict__ emb,
                                                short* __restrict__ hi,
                                                short* __restrict__ lo) {
  const int t = blockIdx.x * 256 + threadIdx.x;  // < 32768
  const int j  = t & 7;
  const int l  = (t >> 3) & 63;
  const int kk = (t >> 9) & 1;
  const int ct = t >> 10;
  const int code = ct * 16 + (l & 15);
  const int k = kk * 32 + ((l >> 4) << 3) + j;
  const float v = emb[code * 64 + k];
  const unsigned short h = bf16rn(v);
  hi[t] = (short)h;
  lo[t] = (short)bf16rn(v - __uint_as_float((unsigned)h << 16));
}

// scoring split-bf16 (proven); gather writes single-bf16 xt for decoder.
__global__ __launch_bounds__(256) void vq_mfma(
    const short* __restrict__ fhi, const short* __restrict__ flo,
    const short* __restrict__ ebh, const short* __restrict__ ebl,
    const float* __restrict__ nrm, const float* __restrict__ emb,
    short* __restrict__ d1h) {
  __shared__ int sidx[64];
  const int lane = threadIdx.x & 63;
  const int wave = threadIdx.x >> 6;
  const int r0 = blockIdx.x * 64 + wave * 16;
  const size_t abase = ((size_t)(r0 + (lane & 15))) * 64 + ((lane >> 4) << 3);
  short8 ah0 = *(const short8*)(fhi + abase);
  short8 ah1 = *(const short8*)(fhi + abase + 32);
  short8 al0 = *(const short8*)(flo + abase);
  short8 al1 = *(const short8*)(flo + abase + 32);

  float bestv[4] = {3.4e38f, 3.4e38f, 3.4e38f, 3.4e38f};
  int   besti[4] = {0, 0, 0, 0};
  const short8* __restrict__ ebh8 = (const short8*)ebh;
  const short8* __restrict__ ebl8 = (const short8*)ebl;
  for (int ct = 0; ct < 32; ++ct) {
    const int f0 = (ct * 2) * 64 + lane;
    const short8 b0h = ebh8[f0];
    const short8 b1h = ebh8[f0 + 64];
    const short8 b0l = ebl8[f0];
    const short8 b1l = ebl8[f0 + 64];
    floatx4 acc = {0.f, 0.f, 0.f, 0.f};
    acc = __builtin_amdgcn_mfma_f32_16x16x32_bf16(ah0, b0h, acc, 0, 0, 0);
    acc = __builtin_amdgcn_mfma_f32_16x16x32_bf16(ah1, b1h, acc, 0, 0, 0);
    acc = __builtin_amdgcn_mfma_f32_16x16x32_bf16(ah0, b0l, acc, 0, 0, 0);
    acc = __builtin_amdgcn_mfma_f32_16x16x32_bf16(ah1, b1l, acc, 0, 0, 0);
    acc = __builtin_amdgcn_mfma_f32_16x16x32_bf16(al0, b0h, acc, 0, 0, 0);
    acc = __builtin_amdgcn_mfma_f32_16x16x32_bf16(al1, b1h, acc, 0, 0, 0);
    const int code = ct * 16 + (lane & 15);
    const float nn = nrm[code];
#pragma unroll
    for (int q = 0; q < 4; ++q) {
      const float sc = nn - 2.f * acc[q];
      if (sc < bestv[q]) { bestv[q] = sc; besti[q] = code; }
    }
  }
#pragma unroll
  for (int off = 1; off < 16; off <<= 1) {
#pragma unroll
    for (int q = 0; q < 4; ++q) {
      const float ov = __shfl_xor(bestv[q], off, 64);
      const int   oi = __shfl_xor(besti[q], off, 64);
      if (ov < bestv[q] || (ov == bestv[q] && oi < besti[q])) {
        bestv[q] = ov; besti[q] = oi;
      }
    }
  }
  if ((lane & 15) == 0) {
#pragma unroll
    for (int q = 0; q < 4; ++q)
      sidx[wave * 16 + (lane >> 4) * 4 + q] = besti[q];
  }
  __syncthreads();
  const int row  = threadIdx.x >> 2;
  const int part = threadIdx.x & 3;
  const int rid = blockIdx.x * 64 + row;
  const int n  = rid >> 11;
  const int ch = (rid >> 4) & 127;
  const int pb = rid & 15;
  const int gi = sidx[row];
  const float4* src = (const float4*)(emb + (size_t)gi * 64 + part * 16);
  float4 v0 = src[0], v1 = src[1], v2 = src[2], v3 = src[3];
  float vals[16] = {v0.x, v0.y, v0.z, v0.w, v1.x, v1.y, v1.z, v1.w,
                    v2.x, v2.y, v2.z, v2.w, v3.x, v3.y, v3.z, v3.w};
#pragma unroll
  for (int kk = 0; kk < 16; ++kk) {
    const int k = part * 16 + kk;
    const int pix = pb * 64 + k;
    const int r = pix >> 5, c = pix & 31;
    const size_t a = (((size_t)n * 34 + r + 1) * 34 + (c + 1)) * 128 + ch;
    d1h[a] = (short)bf16rn(vals[kk]);
  }
}

// ---------------- dec3: fp32 direct from single-bf16 xt input -------------
__global__ __launch_bounds__(256) void dec3_xt(const short* __restrict__ xh,
                                               const float* __restrict__ w,
                                               const float* __restrict__ bias,
                                               float* __restrict__ out, int NH) {
  int t = blockIdx.x * 256 + threadIdx.x;
  if (t >= NH * 128 * 128) return;
  const int px = t & 16383;
  const int nl = t >> 14;
  const int i = px >> 7, j = px & 127;
  const float b0 = bias[0];
  float a00 = b0, a01 = b0, a10 = b0, a11 = b0;
  const size_t base00 = (((size_t)nl * 130 + i + 1) * 130 + (j + 1)) * 32;
#pragma unroll
  for (int icg = 0; icg < 4; ++icg) {
    const short8 h00 = *(const short8*)(xh + base00 + icg * 8);
    const short8 h01 = *(const short8*)(xh + base00 + 32 + icg * 8);
    const short8 h10 = *(const short8*)(xh + base00 + 130 * 32 + icg * 8);
    const short8 h11 = *(const short8*)(xh + base00 + 130 * 32 + 32 + icg * 8);
#pragma unroll
    for (int kk = 0; kk < 8; ++kk) {
      const int ic = icg * 8 + kk;
      const float x00 = bf2f1(h00[kk]);
      const float x01 = bf2f1(h01[kk]);
      const float x10 = bf2f1(h10[kk]);
      const float x11 = bf2f1(h11[kk]);
      const float* wp = w + ic * 9;
      a00 = fmaf(x00, wp[4], a00);
      a01 = fmaf(x00, wp[5], fmaf(x01, wp[3], a01));
      a10 = fmaf(x00, wp[7], fmaf(x10, wp[1], a10));
      a11 = fmaf(x00, wp[8], fmaf(x01, wp[6], fmaf(x10, wp[2], fmaf(x11, wp[0], a11))));
    }
  }
  float* op = out + ((size_t)nl * 256 + 2 * i) * 256 + 2 * j;
  op[0] = a00; op[1] = a01; op[256] = a10; op[257] = a11;
}

// ---------------------------------------------------------------------------
extern "C" void kernel_launch(void* const* d_in, const int* in_sizes, int n_in,
                              void* d_out, int out_size, void* d_ws, size_t ws_size,
                              hipStream_t stream) {
  const float* x   = (const float*)d_in[0];
  const float* w1  = (const float*)d_in[1];
  const float* b1  = (const float*)d_in[2];
  const float* w2  = (const float*)d_in[3];
  const float* b2  = (const float*)d_in[4];
  const float* w3  = (const float*)d_in[5];
  const float* b3  = (const float*)d_in[6];
  const float* w4  = (const float*)d_in[7];
  const float* b4  = (const float*)d_in[8];
  const float* emb = (const float*)d_in[9];
  const float* dw1 = (const float*)d_in[10];
  const float* db1 = (const float*)d_in[11];
  const float* dw2 = (const float*)d_in[12];
  const float* db2 = (const float*)d_in[13];
  const float* dw3 = (const float*)d_in[14];
  const float* db3 = (const float*)d_in[15];
  float* outp = (float*)d_out;

  const int N = in_sizes[0] / (2 * 256 * 256);  // 64
  if (N & 1) return;
  const int NH = N / 2;

  // ---- arena (units: floats; 1 float = 2 shorts); R7-proven footprint ----
  const size_t sx3 = (size_t)N * 66 * 66 * 64;
  const size_t sx2 = (size_t)NH * 130 * 130 * 32;
  const size_t sx4 = (size_t)N * 34 * 34 * 128;
  const size_t se  = (size_t)N * 128 * 1024;
  const size_t sd1 = sx4;
  const size_t smalls = 512 + 18432 + 73728 + 147456 + 73728 + 18432 + 32768;
  const size_t need = (sx3 + sx4 + se + sd1 + smalls) * sizeof(float);
  if (ws_size < need) return;

  float* ws = (float*)d_ws;
  short* x3h = (short*)ws;                 short* x3l = x3h + sx3;   // enc split
  short* x2h = (short*)(ws + sx3);         short* x2l = x2h + sx2;
  short* x4h = (short*)(ws + sx3);         short* x4l = x4h + sx4;
  short* ech = (short*)(ws + sx3 + sx4);   short* ecl = ech + se;
  short* d1h = (short*)(ws + sx3 + sx4 + se);   // bf16-only decoder bufs
  short* d2h = (short*)ws;
  short* d3h = (short*)(ws + sx3);
  float* sm  = ws + sx3 + sx4 + se + sd1;
  float* nrm = sm;
  short* a2h = (short*)(sm + 512);                         short* a2l = a2h + 18432;
  short* a3h = (short*)(sm + 512 + 18432);                 short* a3l = a3h + 73728;
  short* a4h = (short*)(sm + 512 + 18432 + 73728);         short* a4l = a4h + 147456;
  short* ad1h = (short*)(sm + 512 + 18432 + 73728 + 147456);           // hi only
  short* ad2h = (short*)(sm + 512 + 18432 + 73728 + 147456 + 73728);   // hi only
  short* ebh = (short*)(sm + 512 + 18432 + 73728 + 147456 + 73728 + 18432); short* ebl = ebh + 32768;

  // ---- weight preps + VQ tables ----
  wprep_conv<32, 64><<<72, 256, 0, stream>>>(w2, a2h, a2l);
  wprep_conv<64, 128><<<288, 256, 0, stream>>>(w3, a3h, a3l);
  wprep_conv<128, 128><<<576, 256, 0, stream>>>(w4, a4h, a4l);
  wprep_dec_h<128, 64><<<288, 256, 0, stream>>>(dw1, ad1h);
  wprep_dec_h<64, 32><<<72, 256, 0, stream>>>(dw2, ad2h);
  vq_norms<<<2, 256, 0, stream>>>(emb, nrm);
  emb_prep<<<128, 256, 0, stream>>>(emb, ebh, ebl);

  // ---- encoder (split-bf16, unchanged) ----
  ring_zero<<<(int)((NH * 516 * 32 + 255) / 256), 256, 0, stream>>>(x2h, x2l, NH, 130, 130, 32);
  ring_zero<<<(int)(((size_t)N * 260 * 64 + 255) / 256), 256, 0, stream>>>(x3h, x3l, N, 66, 66, 64);
  for (int half = 0; half < 2; ++half) {
    const int n0 = half * NH;
    conv1_xt<<<NH * 16384 / 256, 256, 0, stream>>>(
        x + (size_t)n0 * 2 * 65536, w1, b1, x2h, x2l, NH);
    conv_mfma_xt<32, 64, 64, 64, 2, 130, 130, 66, 66>
        <<<NH * 64, 256, 0, stream>>>(x2h, x2l, a2h, a2l, b2,
                                      x3h + (size_t)n0 * 66 * 66 * 64,
                                      x3l + (size_t)n0 * 66 * 66 * 64);
  }
  ring_zero<<<(int)(((size_t)N * 132 * 128 + 255) / 256), 256, 0, stream>>>(x4h, x4l, N, 34, 34, 128);
  conv_mfma_xt<64, 128, 32, 32, 2, 66, 66, 34, 34>
      <<<N * 16, 256, 0, stream>>>(x3h, x3l, a3h, a3l, b3, x4h, x4l);
  conv4_mfma<<<N * 16, 256, 0, stream>>>(x4h, x4l, a4h, a4l, b4, ech, ecl);

  // ---- VQ (split scoring, bf16 gather) ----
  ring_zero1<<<(int)(((size_t)N * 132 * 128 + 255) / 256), 256, 0, stream>>>(d1h, N, 34, 34, 128);
  vq_mfma<<<N * 2048 / 64, 256, 0, stream>>>(ech, ecl, ebh, ebl, nrm, emb, d1h);

  // ---- decoder (plain bf16, NP=2) ----
  ring_zero1<<<(int)(((size_t)N * 260 * 64 + 255) / 256), 256, 0, stream>>>(d2h, N, 66, 66, 64);
  deconv_bf16_xt<128, 64, 32, 32, 34, 34, 66, 66, 2>
      <<<N * 8, 256, 0, stream>>>(d1h, ad1h, db1, d2h);
  ring_zero1<<<(int)((NH * 516 * 32 + 255) / 256), 256, 0, stream>>>(d3h, NH, 130, 130, 32);
  for (int half = 0; half < 2; ++half) {
    const int n0 = half * NH;
    deconv_bf16_xt<64, 32, 64, 64, 66, 66, 130, 130, 2>
        <<<NH * 32, 256, 0, stream>>>(d2h + (size_t)n0 * 66 * 66 * 64,
                                      ad2h, db2, d3h);
    dec3_xt<<<NH * 16384 / 256, 256, 0, stream>>>(
        d3h, dw3, db3, outp + (size_t)n0 * 65536, NH);
  }
}

// Round 9
// 657.657 us; speedup vs baseline: 4.3843x; 1.0375x over previous
//
#include <hip/hip_runtime.h>

// ---------------------------------------------------------------------------
// VQ-VAE forward (NCHW). Round 9: NP=2 pixel-tiling for encoder MFMA kernels.
//  R8 post-mortem: conv4 latency-bound (MfmaUtil 20%) — 16 A-frag loads per
//  24 MFMAs per tap, A-frags re-loaded per wave. Same fix as deconv R7->R8:
//  each wave handles NP=2 16-pixel tiles so every A-load feeds 2 MFMAs and
//  accumulation chains double. Numerics identical (same products, same
//  per-acc order) -> absmax must stay 2.44e-4 exactly.
//  Decoder (bf16 NP=2), VQ, conv1, dec3 unchanged from R8.
// ---------------------------------------------------------------------------

using short8  = __attribute__((ext_vector_type(8))) short;
using short4v = __attribute__((ext_vector_type(4))) short;
using floatx4 = __attribute__((ext_vector_type(4))) float;

__device__ inline unsigned short bf16rn(float f) {
  unsigned u = __float_as_uint(f);
  unsigned r = (u + 0x7fffu + ((u >> 16) & 1u)) >> 16;
  return (unsigned short)r;
}
__device__ inline float bf2f1(short h) {
  return __uint_as_float(((unsigned)(unsigned short)h) << 16);
}

// ---- deconv tap tables: entry e -> (ky,kx) weight tap
__device__ const int DKY[9]  = {1, 1, 1, 2, 0, 2, 2, 0, 0};
__device__ const int DKX[9]  = {1, 2, 0, 1, 1, 2, 0, 2, 0};

// ---------------- ring zero (split pair) ----------------------------------
__global__ __launch_bounds__(256) void ring_zero(short* __restrict__ h,
                                                 short* __restrict__ l,
                                                 int nimg, int PH, int PW, int C) {
  const int RC = (2 * PW + 2 * (PH - 2)) * C;
  int t = blockIdx.x * 256 + threadIdx.x;
  if (t >= nimg * RC) return;
  const int nl = t / RC;
  int rem = t - nl * RC;
  const int p = rem / C;
  const int ch = rem - p * C;
  int r, c;
  if (p < 2 * PW) {
    r = (p < PW) ? 0 : PH - 1;
    c = (p < PW) ? p : p - PW;
  } else {
    int q = p - 2 * PW;
    if (q < PH - 2) { r = 1 + q; c = 0; }
    else { r = 1 + q - (PH - 2); c = PW - 1; }
  }
  const size_t a = (((size_t)nl * PH + r) * PW + c) * C + ch;
  h[a] = 0; l[a] = 0;
}

// ---------------- ring zero (single buffer) -------------------------------
__global__ __launch_bounds__(256) void ring_zero1(short* __restrict__ h,
                                                  int nimg, int PH, int PW, int C) {
  const int RC = (2 * PW + 2 * (PH - 2)) * C;
  int t = blockIdx.x * 256 + threadIdx.x;
  if (t >= nimg * RC) return;
  const int nl = t / RC;
  int rem = t - nl * RC;
  const int p = rem / C;
  const int ch = rem - p * C;
  int r, c;
  if (p < 2 * PW) {
    r = (p < PW) ? 0 : PH - 1;
    c = (p < PW) ? p : p - PW;
  } else {
    int q = p - 2 * PW;
    if (q < PH - 2) { r = 1 + q; c = 0; }
    else { r = 1 + q - (PH - 2); c = PW - 1; }
  }
  h[(((size_t)nl * PH + r) * PW + c) * C + ch] = 0;
}

// ---------------- conv1: fp32 direct, writes xt [nh][130][130][32] --------
__global__ __launch_bounds__(256) void conv1_xt(const float* __restrict__ x,
                                                const float* __restrict__ w,
                                                const float* __restrict__ bias,
                                                short* __restrict__ oh,
                                                short* __restrict__ ol, int NH) {
  int t = blockIdx.x * 256 + threadIdx.x;
  if (t >= NH * 128 * 128) return;
  const int px = t & 16383;
  const int n  = t >> 14;
  const int r = px >> 7, c = px & 127;
  const int ih0 = 2 * r - 1, iw0 = 2 * c - 1;
  float acc[32];
#pragma unroll
  for (int o = 0; o < 32; ++o) acc[o] = bias[o];
  const float* ip = x + (size_t)n * 2 * 65536;
#pragma unroll
  for (int ic = 0; ic < 2; ++ic, ip += 65536) {
    float v[9];
#pragma unroll
    for (int kh = 0; kh < 3; ++kh) {
      const int ih = ih0 + kh;
#pragma unroll
      for (int kw = 0; kw < 3; ++kw) {
        const int iw = iw0 + kw;
        const bool ok = (ih >= 0) && (ih < 256) && (iw >= 0) && (iw < 256);
        v[kh * 3 + kw] = ok ? ip[ih * 256 + iw] : 0.f;
      }
    }
#pragma unroll
    for (int o = 0; o < 32; ++o) {
      float s = acc[o];
#pragma unroll
      for (int k = 0; k < 9; ++k) s = fmaf(v[k], w[(o * 2 + ic) * 9 + k], s);
      acc[o] = s;
    }
  }
  const size_t base = (((size_t)n * 130 + r + 1) * 130 + (c + 1)) * 32;
  short8 vh[4], vl[4];
#pragma unroll
  for (int g = 0; g < 4; ++g) {
#pragma unroll
    for (int kk = 0; kk < 8; ++kk) {
      const float rv = fmaxf(acc[g * 8 + kk], 0.f);
      const unsigned short hh = bf16rn(rv);
      vh[g][kk] = (short)hh;
      vl[g][kk] = (short)bf16rn(rv - __uint_as_float((unsigned)hh << 16));
    }
    *(short8*)(oh + base + g * 8) = vh[g];
    *(short8*)(ol + base + g * 8) = vl[g];
  }
}

// ---------------- A-frag prep: conv weights [COUT][CIN][3][3], split ------
template<int CIN, int COUT>
__global__ __launch_bounds__(256) void wprep_conv(const float* __restrict__ w,
                                                  short* __restrict__ hi,
                                                  short* __restrict__ lo) {
  constexpr int MT = COUT / 16;
  const int t = blockIdx.x * 256 + threadIdx.x;
  const int j = t & 7;
  const int lane = (t >> 3) & 63;
  const int g = t >> 9;
  const int mt = g % MT;
  const int s = g / MT;
  const int icb = s / 9, tap = s - icb * 9;
  const int kh = tap / 3, kw = tap - kh * 3;
  const int m = mt * 16 + (lane & 15);
  const int ic = icb * 32 + ((lane >> 4) << 3) + j;
  const float v = w[((m * CIN + ic) * 3 + kh) * 3 + kw];
  const unsigned short h = bf16rn(v);
  hi[t] = (short)h;
  lo[t] = (short)bf16rn(v - __uint_as_float((unsigned)h << 16));
}

// ---------------- deconv A-frag prep: [CIN][COUT][3][3], hi-only ----------
template<int CIN, int COUT>
__global__ __launch_bounds__(256) void wprep_dec_h(const float* __restrict__ w,
                                                   short* __restrict__ hi) {
  constexpr int MT = COUT / 16, ICB = CIN / 32;
  const int t = blockIdx.x * 256 + threadIdx.x;
  const int j = t & 7;
  const int lane = (t >> 3) & 63;
  const int g = t >> 9;
  const int mt = g % MT;
  const int u = g / MT;
  const int icb = u % ICB;
  const int e = u / ICB;
  const int ky = DKY[e], kx = DKX[e];
  const int m = mt * 16 + (lane & 15);
  const int ic = icb * 32 + ((lane >> 4) << 3) + j;
  hi[t] = (short)bf16rn(w[((ic * COUT + m) * 3 + ky) * 3 + kx]);
}

// ------- generic strided conv MFMA (split xt -> split xt), NP tiles -------
template<int CIN, int COUT, int OH, int OW, int S, int PHI, int PWI, int PHO, int PWO, int NP>
__global__ __launch_bounds__(256) void conv_mfma_xt(
    const short* __restrict__ xih, const short* __restrict__ xil,
    const short* __restrict__ ah,  const short* __restrict__ al,
    const float* __restrict__ bias,
    short* __restrict__ xoh, short* __restrict__ xol) {
  constexpr int MT = COUT / 16, ICB = CIN / 32;
  constexpr int PXB = 64 * NP, TPB = OH * OW / PXB;
  const int b = blockIdx.x;
  const int n = b / TPB, pt = b % TPB;
  const int lane = threadIdx.x & 63, wave = threadIdx.x >> 6;
  const int quad = lane >> 4;
  int rr[NP], cc[NP];
  size_t bbase[NP];
#pragma unroll
  for (int p = 0; p < NP; ++p) {
    const int pl = pt * PXB + wave * (16 * NP) + p * 16 + (lane & 15);
    rr[p] = pl / OW; cc[p] = pl % OW;
    bbase[p] = (((size_t)n * PHI + S * rr[p]) * PWI + S * cc[p]) * CIN + quad * 8;
  }

  floatx4 acc[MT][NP];
#pragma unroll
  for (int mt = 0; mt < MT; ++mt)
#pragma unroll
    for (int p = 0; p < NP; ++p) acc[mt][p] = (floatx4){0.f, 0.f, 0.f, 0.f};

  const short8* __restrict__ ah8 = (const short8*)ah;
  const short8* __restrict__ al8 = (const short8*)al;

  for (int icb = 0; icb < ICB; ++icb) {
#pragma unroll
    for (int tap = 0; tap < 9; ++tap) {
      const int kh = tap / 3, kw = tap - kh * 3;
      short8 bh[NP], bl[NP];
#pragma unroll
      for (int p = 0; p < NP; ++p) {
        const size_t be = bbase[p] + (size_t)(kh * PWI + kw) * CIN + icb * 32;
        bh[p] = *(const short8*)(xih + be);
        bl[p] = *(const short8*)(xil + be);
      }
#pragma unroll
      for (int mt = 0; mt < MT; ++mt) {
        const int fi = ((icb * 9 + tap) * MT + mt) * 64 + lane;
        const short8 wh = ah8[fi];
        const short8 wl = al8[fi];
#pragma unroll
        for (int p = 0; p < NP; ++p) {
          acc[mt][p] = __builtin_amdgcn_mfma_f32_16x16x32_bf16(wh, bh[p], acc[mt][p], 0, 0, 0);
          acc[mt][p] = __builtin_amdgcn_mfma_f32_16x16x32_bf16(wh, bl[p], acc[mt][p], 0, 0, 0);
          acc[mt][p] = __builtin_amdgcn_mfma_f32_16x16x32_bf16(wl, bh[p], acc[mt][p], 0, 0, 0);
        }
      }
    }
  }
#pragma unroll
  for (int p = 0; p < NP; ++p) {
    const size_t ob = (((size_t)n * PHO + rr[p] + 1) * PWO + (cc[p] + 1)) * COUT + quad * 4;
#pragma unroll
    for (int mt = 0; mt < MT; ++mt) {
      short4v sh, sl;
#pragma unroll
      for (int q = 0; q < 4; ++q) {
        const float v = fmaxf(acc[mt][p][q] + bias[mt * 16 + quad * 4 + q], 0.f);
        const unsigned short hh = bf16rn(v);
        sh[q] = (short)hh;
        sl[q] = (short)bf16rn(v - __uint_as_float((unsigned)hh << 16));
      }
      *(short4v*)(xoh + ob + mt * 16) = sh;
      *(short4v*)(xol + ob + mt * 16) = sl;
    }
  }
}

// ---- fused transposed conv, plain bf16, NP pixel-tiles per wave (R8) -----
template<int CIN, int COUT, int IH, int IW, int PHI, int PWI, int PHO, int PWO, int NP>
__global__ __launch_bounds__(256) void deconv_bf16_xt(
    const short* __restrict__ xih, const short* __restrict__ ah,
    const float* __restrict__ bias, short* __restrict__ xoh) {
  constexpr int MT = COUT / 16, ICB = CIN / 32;
  constexpr int PXB = 64 * NP, TPB = IH * IW / PXB;
  constexpr int PHE[9] = {0, 1, 1, 2, 2, 3, 3, 3, 3};
  constexpr int DE[9]  = {0, 0, 1, 0, 2, 0, 1, 2, 3};
  const int b = blockIdx.x;
  const int n = b / TPB, pt = b % TPB;
  const int lane = threadIdx.x & 63, wave = threadIdx.x >> 6;
  const int quad = lane >> 4;
  int ii[NP], jj[NP];
  size_t p00[NP];
#pragma unroll
  for (int p = 0; p < NP; ++p) {
    const int pl = pt * PXB + wave * (16 * NP) + p * 16 + (lane & 15);
    ii[p] = pl / IW; jj[p] = pl % IW;
    p00[p] = (((size_t)n * PHI + (ii[p] + 1)) * PWI + (jj[p] + 1)) * CIN + quad * 8;
  }

  floatx4 acc[4][MT][NP];
#pragma unroll
  for (int ph = 0; ph < 4; ++ph)
#pragma unroll
    for (int mt = 0; mt < MT; ++mt)
#pragma unroll
      for (int p = 0; p < NP; ++p) acc[ph][mt][p] = (floatx4){0.f, 0.f, 0.f, 0.f};

  const short8* __restrict__ ah8 = (const short8*)ah;
  for (int icb = 0; icb < ICB; ++icb) {
    short8 bh[NP][4];
#pragma unroll
    for (int p = 0; p < NP; ++p)
#pragma unroll
      for (int d = 0; d < 4; ++d)
        bh[p][d] = *(const short8*)(xih + p00[p] +
                                    (size_t)((d >> 1) * PWI + (d & 1)) * CIN + icb * 32);
#pragma unroll
    for (int e = 0; e < 9; ++e) {
      const int ph = PHE[e], d = DE[e];
#pragma unroll
      for (int mt = 0; mt < MT; ++mt) {
        const short8 wh = ah8[((e * ICB + icb) * MT + mt) * 64 + lane];
#pragma unroll
        for (int p = 0; p < NP; ++p)
          acc[ph][mt][p] = __builtin_amdgcn_mfma_f32_16x16x32_bf16(
              wh, bh[p][d], acc[ph][mt][p], 0, 0, 0);
      }
    }
  }
#pragma unroll
  for (int p = 0; p < NP; ++p)
#pragma unroll
    for (int ph = 0; ph < 4; ++ph) {
      const int oy = 2 * ii[p] + (ph >> 1), ox = 2 * jj[p] + (ph & 1);
      const size_t ob = (((size_t)n * PHO + oy + 1) * PWO + (ox + 1)) * COUT + quad * 4;
#pragma unroll
      for (int mt = 0; mt < MT; ++mt) {
        short4v sh;
#pragma unroll
        for (int q = 0; q < 4; ++q)
          sh[q] = (short)bf16rn(fmaxf(acc[ph][mt][p][q] + bias[mt * 16 + quad * 4 + q], 0.f));
        *(short4v*)(xoh + ob + mt * 16) = sh;
      }
    }
}

// ---------------- conv4 MFMA, NP=2 (split in, split flat enc out) ---------
__global__ __launch_bounds__(256) void conv4_mfma(
    const short* __restrict__ xthi, const short* __restrict__ xtlo,
    const short* __restrict__ ahi,  const short* __restrict__ alo,
    const float* __restrict__ bias,
    short* __restrict__ ench, short* __restrict__ encl) {
  const int b    = blockIdx.x;         // N*8 blocks, 128 pixels each
  const int n    = b >> 3;
  const int pt   = b & 7;
  const int lane = threadIdx.x & 63;
  const int wave = threadIdx.x >> 6;
  const int kq   = lane >> 4;
  int pl[2];
  size_t bbase[2];
#pragma unroll
  for (int p = 0; p < 2; ++p) {
    pl[p] = pt * 128 + wave * 32 + p * 16 + (lane & 15);
    const int r = pl[p] >> 5, c = pl[p] & 31;
    bbase[p] = (((size_t)n * 34 + r) * 34 + c) * 128 + kq * 8;
  }

  floatx4 acc[8][2];
#pragma unroll
  for (int mt = 0; mt < 8; ++mt)
#pragma unroll
    for (int p = 0; p < 2; ++p) acc[mt][p] = (floatx4){0.f, 0.f, 0.f, 0.f};

  const short8* __restrict__ ah8 = (const short8*)ahi;
  const short8* __restrict__ al8 = (const short8*)alo;

  int s = 0;
  for (int icb = 0; icb < 4; ++icb) {
#pragma unroll
    for (int tap = 0; tap < 9; ++tap, ++s) {
      const int kh = tap / 3, kw = tap - kh * 3;
      short8 bh[2], bl[2];
#pragma unroll
      for (int p = 0; p < 2; ++p) {
        const size_t be = bbase[p] + (size_t)(kh * 34 + kw) * 128 + icb * 32;
        bh[p] = *(const short8*)(xthi + be);
        bl[p] = *(const short8*)(xtlo + be);
      }
#pragma unroll
      for (int mt = 0; mt < 8; ++mt) {
        const int fi = ((s * 8 + mt) << 6) + lane;
        const short8 ah = ah8[fi];
        const short8 al = al8[fi];
#pragma unroll
        for (int p = 0; p < 2; ++p) {
          acc[mt][p] = __builtin_amdgcn_mfma_f32_16x16x32_bf16(ah, bh[p], acc[mt][p], 0, 0, 0);
          acc[mt][p] = __builtin_amdgcn_mfma_f32_16x16x32_bf16(ah, bl[p], acc[mt][p], 0, 0, 0);
          acc[mt][p] = __builtin_amdgcn_mfma_f32_16x16x32_bf16(al, bh[p], acc[mt][p], 0, 0, 0);
        }
      }
    }
  }
#pragma unroll
  for (int p = 0; p < 2; ++p) {
    const size_t obase = (size_t)n * 128 * 1024 + pl[p];
#pragma unroll
    for (int mt = 0; mt < 8; ++mt) {
#pragma unroll
      for (int q = 0; q < 4; ++q) {
        const int cout = mt * 16 + kq * 4 + q;
        const float rr = fmaxf(acc[mt][p][q] + bias[cout], 0.f);
        const unsigned short h = bf16rn(rr);
        const size_t oi = obase + (size_t)cout * 1024;
        ench[oi] = (short)h;
        encl[oi] = (short)bf16rn(rr - __uint_as_float((unsigned)h << 16));
      }
    }
  }
}

// ------------------------------- VQ ---------------------------------------
__global__ __launch_bounds__(256) void vq_norms(const float* __restrict__ emb,
                                                float* __restrict__ norms) {
  int jj = blockIdx.x * 256 + threadIdx.x;
  if (jj < 512) {
    float s = 0.f;
    const float* e = emb + jj * 64;
#pragma unroll
    for (int k = 0; k < 64; ++k) s = fmaf(e[k], e[k], s);
    norms[jj] = s;
  }
}

__global__ __launch_bounds__(256) void emb_prep(const float* __restrict__ emb,
                                                short* __restrict__ hi,
                                                short* __restrict__ lo) {
  const int t = blockIdx.x * 256 + threadIdx.x;  // < 32768
  const int j  = t & 7;
  const int l  = (t >> 3) & 63;
  const int kk = (t >> 9) & 1;
  const int ct = t >> 10;
  const int code = ct * 16 + (l & 15);
  const int k = kk * 32 + ((l >> 4) << 3) + j;
  const float v = emb[code * 64 + k];
  const unsigned short h = bf16rn(v);
  hi[t] = (short)h;
  lo[t] = (short)bf16rn(v - __uint_as_float((unsigned)h << 16));
}

// scoring split-bf16 (proven); gather writes single-bf16 xt for decoder.
__global__ __launch_bounds__(256) void vq_mfma(
    const short* __restrict__ fhi, const short* __restrict__ flo,
    const short* __restrict__ ebh, const short* __restrict__ ebl,
    const float* __restrict__ nrm, const float* __restrict__ emb,
    short* __restrict__ d1h) {
  __shared__ int sidx[64];
  const int lane = threadIdx.x & 63;
  const int wave = threadIdx.x >> 6;
  const int r0 = blockIdx.x * 64 + wave * 16;
  const size_t abase = ((size_t)(r0 + (lane & 15))) * 64 + ((lane >> 4) << 3);
  short8 ah0 = *(const short8*)(fhi + abase);
  short8 ah1 = *(const short8*)(fhi + abase + 32);
  short8 al0 = *(const short8*)(flo + abase);
  short8 al1 = *(const short8*)(flo + abase + 32);

  float bestv[4] = {3.4e38f, 3.4e38f, 3.4e38f, 3.4e38f};
  int   besti[4] = {0, 0, 0, 0};
  const short8* __restrict__ ebh8 = (const short8*)ebh;
  const short8* __restrict__ ebl8 = (const short8*)ebl;
  for (int ct = 0; ct < 32; ++ct) {
    const int f0 = (ct * 2) * 64 + lane;
    const short8 b0h = ebh8[f0];
    const short8 b1h = ebh8[f0 + 64];
    const short8 b0l = ebl8[f0];
    const short8 b1l = ebl8[f0 + 64];
    floatx4 acc = {0.f, 0.f, 0.f, 0.f};
    acc = __builtin_amdgcn_mfma_f32_16x16x32_bf16(ah0, b0h, acc, 0, 0, 0);
    acc = __builtin_amdgcn_mfma_f32_16x16x32_bf16(ah1, b1h, acc, 0, 0, 0);
    acc = __builtin_amdgcn_mfma_f32_16x16x32_bf16(ah0, b0l, acc, 0, 0, 0);
    acc = __builtin_amdgcn_mfma_f32_16x16x32_bf16(ah1, b1l, acc, 0, 0, 0);
    acc = __builtin_amdgcn_mfma_f32_16x16x32_bf16(al0, b0h, acc, 0, 0, 0);
    acc = __builtin_amdgcn_mfma_f32_16x16x32_bf16(al1, b1h, acc, 0, 0, 0);
    const int code = ct * 16 + (lane & 15);
    const float nn = nrm[code];
#pragma unroll
    for (int q = 0; q < 4; ++q) {
      const float sc = nn - 2.f * acc[q];
      if (sc < bestv[q]) { bestv[q] = sc; besti[q] = code; }
    }
  }
#pragma unroll
  for (int off = 1; off < 16; off <<= 1) {
#pragma unroll
    for (int q = 0; q < 4; ++q) {
      const float ov = __shfl_xor(bestv[q], off, 64);
      const int   oi = __shfl_xor(besti[q], off, 64);
      if (ov < bestv[q] || (ov == bestv[q] && oi < besti[q])) {
        bestv[q] = ov; besti[q] = oi;
      }
    }
  }
  if ((lane & 15) == 0) {
#pragma unroll
    for (int q = 0; q < 4; ++q)
      sidx[wave * 16 + (lane >> 4) * 4 + q] = besti[q];
  }
  __syncthreads();
  const int row  = threadIdx.x >> 2;
  const int part = threadIdx.x & 3;
  const int rid = blockIdx.x * 64 + row;
  const int n  = rid >> 11;
  const int ch = (rid >> 4) & 127;
  const int pb = rid & 15;
  const int gi = sidx[row];
  const float4* src = (const float4*)(emb + (size_t)gi * 64 + part * 16);
  float4 v0 = src[0], v1 = src[1], v2 = src[2], v3 = src[3];
  float vals[16] = {v0.x, v0.y, v0.z, v0.w, v1.x, v1.y, v1.z, v1.w,
                    v2.x, v2.y, v2.z, v2.w, v3.x, v3.y, v3.z, v3.w};
#pragma unroll
  for (int kk = 0; kk < 16; ++kk) {
    const int k = part * 16 + kk;
    const int pix = pb * 64 + k;
    const int r = pix >> 5, c = pix & 31;
    const size_t a = (((size_t)n * 34 + r + 1) * 34 + (c + 1)) * 128 + ch;
    d1h[a] = (short)bf16rn(vals[kk]);
  }
}

// ---------------- dec3: fp32 direct from single-bf16 xt input -------------
__global__ __launch_bounds__(256) void dec3_xt(const short* __restrict__ xh,
                                               const float* __restrict__ w,
                                               const float* __restrict__ bias,
                                               float* __restrict__ out, int NH) {
  int t = blockIdx.x * 256 + threadIdx.x;
  if (t >= NH * 128 * 128) return;
  const int px = t & 16383;
  const int nl = t >> 14;
  const int i = px >> 7, j = px & 127;
  const float b0 = bias[0];
  float a00 = b0, a01 = b0, a10 = b0, a11 = b0;
  const size_t base00 = (((size_t)nl * 130 + i + 1) * 130 + (j + 1)) * 32;
#pragma unroll
  for (int icg = 0; icg < 4; ++icg) {
    const short8 h00 = *(const short8*)(xh + base00 + icg * 8);
    const short8 h01 = *(const short8*)(xh + base00 + 32 + icg * 8);
    const short8 h10 = *(const short8*)(xh + base00 + 130 * 32 + icg * 8);
    const short8 h11 = *(const short8*)(xh + base00 + 130 * 32 + 32 + icg * 8);
#pragma unroll
    for (int kk = 0; kk < 8; ++kk) {
      const int ic = icg * 8 + kk;
      const float x00 = bf2f1(h00[kk]);
      const float x01 = bf2f1(h01[kk]);
      const float x10 = bf2f1(h10[kk]);
      const float x11 = bf2f1(h11[kk]);
      const float* wp = w + ic * 9;
      a00 = fmaf(x00, wp[4], a00);
      a01 = fmaf(x00, wp[5], fmaf(x01, wp[3], a01));
      a10 = fmaf(x00, wp[7], fmaf(x10, wp[1], a10));
      a11 = fmaf(x00, wp[8], fmaf(x01, wp[6], fmaf(x10, wp[2], fmaf(x11, wp[0], a11))));
    }
  }
  float* op = out + ((size_t)nl * 256 + 2 * i) * 256 + 2 * j;
  op[0] = a00; op[1] = a01; op[256] = a10; op[257] = a11;
}

// ---------------------------------------------------------------------------
extern "C" void kernel_launch(void* const* d_in, const int* in_sizes, int n_in,
                              void* d_out, int out_size, void* d_ws, size_t ws_size,
                              hipStream_t stream) {
  const float* x   = (const float*)d_in[0];
  const float* w1  = (const float*)d_in[1];
  const float* b1  = (const float*)d_in[2];
  const float* w2  = (const float*)d_in[3];
  const float* b2  = (const float*)d_in[4];
  const float* w3  = (const float*)d_in[5];
  const float* b3  = (const float*)d_in[6];
  const float* w4  = (const float*)d_in[7];
  const float* b4  = (const float*)d_in[8];
  const float* emb = (const float*)d_in[9];
  const float* dw1 = (const float*)d_in[10];
  const float* db1 = (const float*)d_in[11];
  const float* dw2 = (const float*)d_in[12];
  const float* db2 = (const float*)d_in[13];
  const float* dw3 = (const float*)d_in[14];
  const float* db3 = (const float*)d_in[15];
  float* outp = (float*)d_out;

  const int N = in_sizes[0] / (2 * 256 * 256);  // 64
  if (N & 1) return;
  const int NH = N / 2;

  // ---- arena (units: floats; 1 float = 2 shorts); R7-proven footprint ----
  const size_t sx3 = (size_t)N * 66 * 66 * 64;
  const size_t sx2 = (size_t)NH * 130 * 130 * 32;
  const size_t sx4 = (size_t)N * 34 * 34 * 128;
  const size_t se  = (size_t)N * 128 * 1024;
  const size_t sd1 = sx4;
  const size_t smalls = 512 + 18432 + 73728 + 147456 + 73728 + 18432 + 32768;
  const size_t need = (sx3 + sx4 + se + sd1 + smalls) * sizeof(float);
  if (ws_size < need) return;

  float* ws = (float*)d_ws;
  short* x3h = (short*)ws;                 short* x3l = x3h + sx3;   // enc split
  short* x2h = (short*)(ws + sx3);         short* x2l = x2h + sx2;
  short* x4h = (short*)(ws + sx3);         short* x4l = x4h + sx4;
  short* ech = (short*)(ws + sx3 + sx4);   short* ecl = ech + se;
  short* d1h = (short*)(ws + sx3 + sx4 + se);   // bf16-only decoder bufs
  short* d2h = (short*)ws;
  short* d3h = (short*)(ws + sx3);
  float* sm  = ws + sx3 + sx4 + se + sd1;
  float* nrm = sm;
  short* a2h = (short*)(sm + 512);                         short* a2l = a2h + 18432;
  short* a3h = (short*)(sm + 512 + 18432);                 short* a3l = a3h + 73728;
  short* a4h = (short*)(sm + 512 + 18432 + 73728);         short* a4l = a4h + 147456;
  short* ad1h = (short*)(sm + 512 + 18432 + 73728 + 147456);           // hi only
  short* ad2h = (short*)(sm + 512 + 18432 + 73728 + 147456 + 73728);   // hi only
  short* ebh = (short*)(sm + 512 + 18432 + 73728 + 147456 + 73728 + 18432); short* ebl = ebh + 32768;

  // ---- weight preps + VQ tables ----
  wprep_conv<32, 64><<<72, 256, 0, stream>>>(w2, a2h, a2l);
  wprep_conv<64, 128><<<288, 256, 0, stream>>>(w3, a3h, a3l);
  wprep_conv<128, 128><<<576, 256, 0, stream>>>(w4, a4h, a4l);
  wprep_dec_h<128, 64><<<288, 256, 0, stream>>>(dw1, ad1h);
  wprep_dec_h<64, 32><<<72, 256, 0, stream>>>(dw2, ad2h);
  vq_norms<<<2, 256, 0, stream>>>(emb, nrm);
  emb_prep<<<128, 256, 0, stream>>>(emb, ebh, ebl);

  // ---- encoder (split-bf16, NP=2) ----
  ring_zero<<<(int)((NH * 516 * 32 + 255) / 256), 256, 0, stream>>>(x2h, x2l, NH, 130, 130, 32);
  ring_zero<<<(int)(((size_t)N * 260 * 64 + 255) / 256), 256, 0, stream>>>(x3h, x3l, N, 66, 66, 64);
  for (int half = 0; half < 2; ++half) {
    const int n0 = half * NH;
    conv1_xt<<<NH * 16384 / 256, 256, 0, stream>>>(
        x + (size_t)n0 * 2 * 65536, w1, b1, x2h, x2l, NH);
    conv_mfma_xt<32, 64, 64, 64, 2, 130, 130, 66, 66, 2>
        <<<NH * 32, 256, 0, stream>>>(x2h, x2l, a2h, a2l, b2,
                                      x3h + (size_t)n0 * 66 * 66 * 64,
                                      x3l + (size_t)n0 * 66 * 66 * 64);
  }
  ring_zero<<<(int)(((size_t)N * 132 * 128 + 255) / 256), 256, 0, stream>>>(x4h, x4l, N, 34, 34, 128);
  conv_mfma_xt<64, 128, 32, 32, 2, 66, 66, 34, 34, 2>
      <<<N * 8, 256, 0, stream>>>(x3h, x3l, a3h, a3l, b3, x4h, x4l);
  conv4_mfma<<<N * 8, 256, 0, stream>>>(x4h, x4l, a4h, a4l, b4, ech, ecl);

  // ---- VQ (split scoring, bf16 gather) ----
  ring_zero1<<<(int)(((size_t)N * 132 * 128 + 255) / 256), 256, 0, stream>>>(d1h, N, 34, 34, 128);
  vq_mfma<<<N * 2048 / 64, 256, 0, stream>>>(ech, ecl, ebh, ebl, nrm, emb, d1h);

  // ---- decoder (plain bf16, NP=2) ----
  ring_zero1<<<(int)(((size_t)N * 260 * 64 + 255) / 256), 256, 0, stream>>>(d2h, N, 66, 66, 64);
  deconv_bf16_xt<128, 64, 32, 32, 34, 34, 66, 66, 2>
      <<<N * 8, 256, 0, stream>>>(d1h, ad1h, db1, d2h);
  ring_zero1<<<(int)((NH * 516 * 32 + 255) / 256), 256, 0, stream>>>(d3h, NH, 130, 130, 32);
  for (int half = 0; half < 2; ++half) {
    const int n0 = half * NH;
    deconv_bf16_xt<64, 32, 64, 64, 66, 66, 130, 130, 2>
        <<<NH * 32, 256, 0, stream>>>(d2h + (size_t)n0 * 66 * 66 * 64,
                                      ad2h, db2, d3h);
    dec3_xt<<<NH * 16384 / 256, 256, 0, stream>>>(
        d3h, dw3, db3, outp + (size_t)n0 * 65536, NH);
  }
}